// Round 1
// baseline (742.534 us; speedup 1.0000x reference)
//
#include <hip/hip_runtime.h>
#include <math.h>

#define NN 100000
#define NE 1600000

// ---------------- GEMM1: x[N,128] @ w1_l -> y1[N,64];  x @ w1_r + b1 -> h1p[N,64]
__global__ __launch_bounds__(256) void gemm1(const float* __restrict__ x,
    const float* __restrict__ wl, const float* __restrict__ wr,
    const float* __restrict__ b1, float* __restrict__ y1, float* __restrict__ h1p)
{
    __shared__ float swl[128 * 64];
    __shared__ float swr[128 * 64];
    __shared__ float sx[32 * 128];
    const int tid = threadIdx.x;
    for (int i = tid; i < 128 * 64; i += 256) { swl[i] = wl[i]; swr[i] = wr[i]; }
    const int base = blockIdx.x * 32;
    const float* xb = x + (size_t)base * 128;
    for (int i = tid; i < 32 * 128; i += 256) sx[i] = xb[i];
    __syncthreads();

    const int j = tid & 63;        // output feature
    const int nslot = tid >> 6;    // 0..3
    const float bj = b1[j];
    for (int ns = 0; ns < 8; ++ns) {
        const int node = ns * 4 + nslot;
        const float* xr = &sx[node * 128];
        float al = 0.f, ar = 0.f;
#pragma unroll 8
        for (int k = 0; k < 128; ++k) {
            const float xv = xr[k];
            al = fmaf(xv, swl[k * 64 + j], al);
            ar = fmaf(xv, swr[k * 64 + j], ar);
        }
        const size_t o = (size_t)(base + node) * 64 + j;
        y1[o] = al;
        h1p[o] = ar + bj;
    }
}

// ---------------- edge scatter-add, 64-wide feats: agg[dst] += y1[src]; deg[dst] += 1
__global__ __launch_bounds__(256) void edge_agg64(const int* __restrict__ src,
    const int* __restrict__ dst, const float* __restrict__ y1,
    float* __restrict__ agg, float* __restrict__ deg)
{
    const int e = blockIdx.x * 4 + (threadIdx.x >> 6);
    if (e >= NE) return;
    const int lane = threadIdx.x & 63;
    const int s = src[e], d = dst[e];
    const float v = y1[(size_t)s * 64 + lane];
    atomicAdd(&agg[(size_t)d * 64 + lane], v);
    if (lane == 0) atomicAdd(&deg[d], 1.0f);
}

// ---------------- finalize: h[i] += agg[i] / max(deg,1)   (DW = feat width)
template <int DW>
__global__ void finalize(float* __restrict__ h, const float* __restrict__ agg,
                         const float* __restrict__ deg)
{
    const size_t i = (size_t)blockIdx.x * blockDim.x + threadIdx.x;
    if (i >= (size_t)NN * DW) return;
    const float dg = deg[i / DW];
    const float r = 1.0f / fmaxf(dg, 1.0f);
    h[i] = fmaf(agg[i], r, h[i]);
}

// ---------------- GEMM2: h1[N,64] @ w2_l -> z2[N,16];  h1 @ w2_r + b2 -> h2p[N,16]
__global__ __launch_bounds__(256) void gemm2(const float* __restrict__ h1,
    const float* __restrict__ wl, const float* __restrict__ wr,
    const float* __restrict__ b2, float* __restrict__ z2, float* __restrict__ h2p)
{
    __shared__ float swl[64 * 16];
    __shared__ float swr[64 * 16];
    __shared__ float sh[16 * 64];
    const int tid = threadIdx.x;
    for (int i = tid; i < 64 * 16; i += 256) { swl[i] = wl[i]; swr[i] = wr[i]; }
    const int base = blockIdx.x * 16;
    const float* hb = h1 + (size_t)base * 64;
    for (int i = tid; i < 16 * 64; i += 256) sh[i] = hb[i];
    __syncthreads();

    const int j = tid & 15;       // output feature
    const int nslot = tid >> 4;   // 0..15 node within tile
    const float* hr = &sh[nslot * 64];
    float al = 0.f, ar = 0.f;
#pragma unroll 8
    for (int k = 0; k < 64; ++k) {
        const float hv = hr[k];
        al = fmaf(hv, swl[k * 16 + j], al);
        ar = fmaf(hv, swr[k * 16 + j], ar);
    }
    const size_t o = (size_t)(base + nslot) * 16 + j;
    z2[o] = al;
    h2p[o] = ar + b2[j];
}

// ---------------- edge scatter-add, 16-wide feats
__global__ __launch_bounds__(256) void edge_agg16(const int* __restrict__ src,
    const int* __restrict__ dst, const float* __restrict__ z2,
    float* __restrict__ agg)
{
    const int e = blockIdx.x * 16 + (threadIdx.x >> 4);
    if (e >= NE) return;
    const int f = threadIdx.x & 15;
    const int s = src[e], d = dst[e];
    atomicAdd(&agg[(size_t)d * 16 + f], z2[(size_t)s * 16 + f]);
}

// ---------------- collapse MLP head: v[k] = sum_j fc1_w[k,j]*fc2_w[j]; c = fc1_b.fc2_w + fc2_b
__global__ void precomp_head(const float* __restrict__ fc1w, const float* __restrict__ fc1b,
                             const float* __restrict__ fc2w, const float* __restrict__ fc2b,
                             float* __restrict__ vbuf)
{
    const int k = threadIdx.x;
    if (k < 16) {
        float acc = 0.f;
        for (int j = 0; j < 8; ++j) acc += fc1w[k * 8 + j] * fc2w[j];
        vbuf[k] = acc;
    }
    if (k == 16) {
        float c = fc2b[0];
        for (int j = 0; j < 8; ++j) c += fc1b[j] * fc2w[j];
        vbuf[16] = c;
    }
}

// ---------------- per-edge epilogue: out = sigmoid( sum_k h2[s][k]*h2[d][k]*v[k] + c )
__global__ __launch_bounds__(256) void edge_mlp(const int* __restrict__ src,
    const int* __restrict__ dst, const float* __restrict__ h2,
    const float* __restrict__ vbuf, float* __restrict__ out)
{
    __shared__ float sv[17];
    if (threadIdx.x < 17) sv[threadIdx.x] = vbuf[threadIdx.x];
    __syncthreads();
    const int e = blockIdx.x * 256 + threadIdx.x;
    if (e >= NE) return;
    const int s = src[e], d = dst[e];
    const float4* hs = (const float4*)(h2 + (size_t)s * 16);
    const float4* hd = (const float4*)(h2 + (size_t)d * 16);
    float acc = sv[16];
#pragma unroll
    for (int q = 0; q < 4; ++q) {
        const float4 a = hs[q], b = hd[q];
        acc = fmaf(a.x * b.x, sv[q * 4 + 0], acc);
        acc = fmaf(a.y * b.y, sv[q * 4 + 1], acc);
        acc = fmaf(a.z * b.z, sv[q * 4 + 2], acc);
        acc = fmaf(a.w * b.w, sv[q * 4 + 3], acc);
    }
    out[e] = 1.0f / (1.0f + __expf(-acc));
}

extern "C" void kernel_launch(void* const* d_in, const int* in_sizes, int n_in,
                              void* d_out, int out_size, void* d_ws, size_t ws_size,
                              hipStream_t stream)
{
    const float* x    = (const float*)d_in[0];
    const int*   ei   = (const int*)d_in[1];     // [2, NE] -> src row then dst row
    const float* w1l  = (const float*)d_in[2];
    const float* w1r  = (const float*)d_in[3];
    const float* b1   = (const float*)d_in[4];
    const float* w2l  = (const float*)d_in[5];
    const float* w2r  = (const float*)d_in[6];
    const float* b2   = (const float*)d_in[7];
    const float* fc1w = (const float*)d_in[8];
    const float* fc1b = (const float*)d_in[9];
    const float* fc2w = (const float*)d_in[10];
    const float* fc2b = (const float*)d_in[11];
    float* out = (float*)d_out;

    const int* src = ei;
    const int* dst = ei + NE;

    // workspace layout (floats)
    float* ws   = (float*)d_ws;
    float* deg  = ws;                       // NN
    float* bufA = ws + NN;                  // NN*64  : y1, later z2 (NN*16) + h2 (NN*16)
    float* bufB = ws + NN + (size_t)NN*64;  // NN*64  : agg1, later agg2 (NN*16)
    float* bufC = ws + NN + (size_t)NN*128; // NN*64  : h1
    float* vbuf = ws + NN + (size_t)NN*192; // 17

    float* y1   = bufA;
    float* agg1 = bufB;
    float* h1   = bufC;
    float* z2   = bufA;                 // reuse (NN*16)
    float* h2   = bufA + (size_t)NN*16; // reuse (NN*16)
    float* agg2 = bufB;                 // reuse (NN*16)

    // zero deg + agg1 (agg2 memset happens after agg1 is consumed)
    hipMemsetAsync(deg,  0, (size_t)NN * sizeof(float), stream);
    hipMemsetAsync(agg1, 0, (size_t)NN * 64 * sizeof(float), stream);

    precomp_head<<<1, 64, 0, stream>>>(fc1w, fc1b, fc2w, fc2b, vbuf);

    // layer 1
    gemm1<<<NN / 32, 256, 0, stream>>>(x, w1l, w1r, b1, y1, h1);
    edge_agg64<<<(NE + 3) / 4, 256, 0, stream>>>(src, dst, y1, agg1, deg);
    finalize<64><<<(NN * 64 + 255) / 256, 256, 0, stream>>>(h1, agg1, deg);

    // layer 2
    gemm2<<<NN / 16, 256, 0, stream>>>(h1, w2l, w2r, b2, z2, h2);
    hipMemsetAsync(agg2, 0, (size_t)NN * 16 * sizeof(float), stream);
    edge_agg16<<<(NE + 15) / 16, 256, 0, stream>>>(src, dst, z2, agg2);
    finalize<16><<<(NN * 16 + 255) / 256, 256, 0, stream>>>(h2, agg2, deg);

    // head
    edge_mlp<<<(NE + 255) / 256, 256, 0, stream>>>(src, dst, h2, vbuf, out);
}

// Round 2
// 493.925 us; speedup vs baseline: 1.5033x; 1.5033x over previous
//
#include <hip/hip_runtime.h>
#include <math.h>

#define NN 100000
#define NE 1600000

// ---- A[128][64] = [w1l@w2l | w1l@w2r | w1r@w2l | w1r@w2r]  (cols 0-15,16-31,32-47,48-63)
__global__ __launch_bounds__(64) void precomp_A(const float* __restrict__ w1l,
    const float* __restrict__ w1r, const float* __restrict__ w2l,
    const float* __restrict__ w2r, float* __restrict__ A)
{
    __shared__ float sl[64], sr[64];
    const int k = blockIdx.x;     // 0..127 (input feature)
    const int j = threadIdx.x;    // 0..63  (output column)
    sl[j] = w1l[k * 64 + j];
    sr[j] = w1r[k * 64 + j];
    __syncthreads();
    const int sel = j >> 4, jj = j & 15;
    const float* row = (sel < 2) ? sl : sr;
    const float* w2  = (sel & 1) ? w2r : w2l;
    float acc = 0.f;
#pragma unroll
    for (int m = 0; m < 64; ++m) acc = fmaf(row[m], w2[m * 16 + jj], acc);
    A[k * 64 + j] = acc;
}

// ---- cbuf: [0:16)=b1@w2l  [16:32)=b1@w2r  [32:48)=v=fc1w@fc2w  [48]=c
__global__ void precomp_consts(const float* __restrict__ b1,
    const float* __restrict__ w2l, const float* __restrict__ w2r,
    const float* __restrict__ fc1w, const float* __restrict__ fc1b,
    const float* __restrict__ fc2w, const float* __restrict__ fc2b,
    float* __restrict__ cbuf)
{
    const int j = threadIdx.x;
    if (j < 16) {
        float a = 0.f;
        for (int m = 0; m < 64; ++m) a = fmaf(b1[m], w2l[m * 16 + j], a);
        cbuf[j] = a;
    } else if (j < 32) {
        const int jj = j - 16;
        float a = 0.f;
        for (int m = 0; m < 64; ++m) a = fmaf(b1[m], w2r[m * 16 + jj], a);
        cbuf[j] = a;
    } else if (j < 48) {
        const int k = j - 32;
        float a = 0.f;
        for (int m = 0; m < 8; ++m) a = fmaf(fc1w[k * 8 + m], fc2w[m], a);
        cbuf[j] = a;
    } else if (j == 48) {
        float a = fc2b[0];
        for (int m = 0; m < 8; ++m) a = fmaf(fc1b[m], fc2w[m], a);
        cbuf[48] = a;
    }
}

// ---- y = x @ A;  p = y[:,0:32] (scatter payload), q = y[:,32:64] (root path)
__global__ __launch_bounds__(256) void gemm_pq(const float* __restrict__ x,
    const float* __restrict__ A, float* __restrict__ p, float* __restrict__ q)
{
    __shared__ float sA[128 * 64];
    __shared__ float sx[32 * 128];
    const int tid = threadIdx.x;
    for (int i = tid; i < 128 * 64; i += 256) sA[i] = A[i];
    const int base = blockIdx.x * 32;
    const float* xb = x + (size_t)base * 128;
    for (int i = tid; i < 32 * 128; i += 256) sx[i] = xb[i];
    __syncthreads();

    const int j = tid & 63;       // output column
    const int nslot = tid >> 6;   // 0..3 (uniform per wave -> sx read broadcasts)
    for (int ns = 0; ns < 8; ++ns) {
        const int node = ns * 4 + nslot;
        const float* xr = &sx[node * 128];
        float acc = 0.f;
#pragma unroll 8
        for (int k = 0; k < 128; ++k) acc = fmaf(xr[k], sA[k * 64 + j], acc);
        const int gn = base + node;
        if (j < 32) p[(size_t)gn * 32 + j] = acc;
        else        q[(size_t)gn * 32 + (j - 32)] = acc;
    }
}

// ---- layer-1 scatter: s1[dst] += p[src] (32 wide); deg[dst] += 1
__global__ __launch_bounds__(256) void edge_agg32(const int* __restrict__ src,
    const int* __restrict__ dst, const float* __restrict__ p,
    float* __restrict__ s1, float* __restrict__ deg)
{
    const int e = blockIdx.x * 8 + (threadIdx.x >> 5);
    if (e >= NE) return;
    const int lane = threadIdx.x & 31;
    const int s = src[e], d = dst[e];
    const float v = p[(size_t)s * 32 + lane];
    atomicAdd(&s1[(size_t)d * 32 + lane], v);
    if (lane == 0) atomicAdd(&deg[d], 1.0f);
}

// ---- g = s1_l/deg + q_l + cl ; r = s1_r/deg + q_r + cr
__global__ __launch_bounds__(256) void finalize1(const float* __restrict__ s1,
    const float* __restrict__ deg, const float* __restrict__ q,
    const float* __restrict__ cbuf, float* __restrict__ g, float* __restrict__ r)
{
    const size_t i = (size_t)blockIdx.x * 256 + threadIdx.x;
    if (i >= (size_t)NN * 32) return;
    const int node = (int)(i >> 5), f = (int)(i & 31);
    const float m = s1[i] * (1.0f / fmaxf(deg[node], 1.0f));
    const float val = m + q[i] + cbuf[f];          // cbuf[f] = cl[f] or cr[f-16]
    if (f < 16) g[(size_t)node * 16 + f] = val;
    else        r[(size_t)node * 16 + (f - 16)] = val;
}

// ---- layer-2 scatter: s2[dst] += g[src] (16 wide)
__global__ __launch_bounds__(256) void edge_agg16(const int* __restrict__ src,
    const int* __restrict__ dst, const float* __restrict__ g,
    float* __restrict__ s2)
{
    const int e = blockIdx.x * 16 + (threadIdx.x >> 4);
    if (e >= NE) return;
    const int f = threadIdx.x & 15;
    const int s = src[e], d = dst[e];
    atomicAdd(&s2[(size_t)d * 16 + f], g[(size_t)s * 16 + f]);
}

// ---- h2 = s2/deg + r + b2
__global__ __launch_bounds__(256) void finalize2(const float* __restrict__ s2,
    const float* __restrict__ deg, const float* __restrict__ r,
    const float* __restrict__ b2, float* __restrict__ h2)
{
    const size_t i = (size_t)blockIdx.x * 256 + threadIdx.x;
    if (i >= (size_t)NN * 16) return;
    const int node = (int)(i >> 4), f = (int)(i & 15);
    h2[i] = s2[i] * (1.0f / fmaxf(deg[node], 1.0f)) + r[i] + b2[f];
}

// ---- out = sigmoid( sum_k h2[s][k]*h2[d][k]*v[k] + c )
__global__ __launch_bounds__(256) void edge_mlp(const int* __restrict__ src,
    const int* __restrict__ dst, const float* __restrict__ h2,
    const float* __restrict__ cbuf, float* __restrict__ out)
{
    __shared__ float sv[17];
    if (threadIdx.x < 16) sv[threadIdx.x] = cbuf[32 + threadIdx.x];
    if (threadIdx.x == 16) sv[16] = cbuf[48];
    __syncthreads();
    const int e = blockIdx.x * 256 + threadIdx.x;
    if (e >= NE) return;
    const int s = src[e], d = dst[e];
    const float4* hs = (const float4*)(h2 + (size_t)s * 16);
    const float4* hd = (const float4*)(h2 + (size_t)d * 16);
    float acc = sv[16];
#pragma unroll
    for (int qq = 0; qq < 4; ++qq) {
        const float4 a = hs[qq], b = hd[qq];
        acc = fmaf(a.x * b.x, sv[qq * 4 + 0], acc);
        acc = fmaf(a.y * b.y, sv[qq * 4 + 1], acc);
        acc = fmaf(a.z * b.z, sv[qq * 4 + 2], acc);
        acc = fmaf(a.w * b.w, sv[qq * 4 + 3], acc);
    }
    out[e] = 1.0f / (1.0f + __expf(-acc));
}

extern "C" void kernel_launch(void* const* d_in, const int* in_sizes, int n_in,
                              void* d_out, int out_size, void* d_ws, size_t ws_size,
                              hipStream_t stream)
{
    const float* x    = (const float*)d_in[0];
    const int*   ei   = (const int*)d_in[1];
    const float* w1l  = (const float*)d_in[2];
    const float* w1r  = (const float*)d_in[3];
    const float* b1   = (const float*)d_in[4];
    const float* w2l  = (const float*)d_in[5];
    const float* w2r  = (const float*)d_in[6];
    const float* b2   = (const float*)d_in[7];
    const float* fc1w = (const float*)d_in[8];
    const float* fc1b = (const float*)d_in[9];
    const float* fc2w = (const float*)d_in[10];
    const float* fc2b = (const float*)d_in[11];
    float* out = (float*)d_out;

    const int* src = ei;
    const int* dst = ei + NE;

    // workspace layout (floats)
    float* ws   = (float*)d_ws;
    float* A    = ws;                                   // 8192
    float* cbuf = ws + 8192;                            // 64
    float* deg  = ws + 8256;                            // NN
    float* p    = deg + NN;                             // NN*32
    float* q    = p + (size_t)NN * 32;                  // NN*32
    float* s1   = q + (size_t)NN * 32;                  // NN*32
    float* g    = s1 + (size_t)NN * 32;                 // NN*16
    float* r    = g + (size_t)NN * 16;                  // NN*16
    float* s2   = r + (size_t)NN * 16;                  // NN*16
    float* h2   = s2 + (size_t)NN * 16;                 // NN*16

    hipMemsetAsync(deg, 0, (size_t)NN * sizeof(float), stream);
    hipMemsetAsync(s1,  0, (size_t)NN * 32 * sizeof(float), stream);
    hipMemsetAsync(s2,  0, (size_t)NN * 16 * sizeof(float), stream);

    precomp_A<<<128, 64, 0, stream>>>(w1l, w1r, w2l, w2r, A);
    precomp_consts<<<1, 64, 0, stream>>>(b1, w2l, w2r, fc1w, fc1b, fc2w, fc2b, cbuf);

    gemm_pq<<<NN / 32, 256, 0, stream>>>(x, A, p, q);

    edge_agg32<<<NE / 8, 256, 0, stream>>>(src, dst, p, s1, deg);
    finalize1<<<(NN * 32 + 255) / 256, 256, 0, stream>>>(s1, deg, q, cbuf, g, r);

    edge_agg16<<<NE / 16, 256, 0, stream>>>(src, dst, g, s2);
    finalize2<<<(NN * 16 + 255) / 256, 256, 0, stream>>>(s2, deg, r, b2, h2);

    edge_mlp<<<NE / 256, 256, 0, stream>>>(src, dst, h2, cbuf, out);
}

// Round 3
// 439.454 us; speedup vs baseline: 1.6897x; 1.1240x over previous
//
#include <hip/hip_runtime.h>
#include <math.h>

#define NN 100000
#define NE 1600000
#define SCAN_BLK 1024
#define NSCAN ((NN + SCAN_BLK - 1) / SCAN_BLK)   // 98

// ---- A[128][64] = [w1l@w2l | w1l@w2r | w1r@w2l | w1r@w2r]
__global__ __launch_bounds__(64) void precomp_A(const float* __restrict__ w1l,
    const float* __restrict__ w1r, const float* __restrict__ w2l,
    const float* __restrict__ w2r, float* __restrict__ A)
{
    __shared__ float sl[64], sr[64];
    const int k = blockIdx.x;
    const int j = threadIdx.x;
    sl[j] = w1l[k * 64 + j];
    sr[j] = w1r[k * 64 + j];
    __syncthreads();
    const int sel = j >> 4, jj = j & 15;
    const float* row = (sel < 2) ? sl : sr;
    const float* w2  = (sel & 1) ? w2r : w2l;
    float acc = 0.f;
#pragma unroll
    for (int m = 0; m < 64; ++m) acc = fmaf(row[m], w2[m * 16 + jj], acc);
    A[k * 64 + j] = acc;
}

// ---- cbuf: [0:16)=b1@w2l  [16:32)=b1@w2r  [32:48)=v=fc1w@fc2w  [48]=c
__global__ void precomp_consts(const float* __restrict__ b1,
    const float* __restrict__ w2l, const float* __restrict__ w2r,
    const float* __restrict__ fc1w, const float* __restrict__ fc1b,
    const float* __restrict__ fc2w, const float* __restrict__ fc2b,
    float* __restrict__ cbuf)
{
    const int j = threadIdx.x;
    if (j < 16) {
        float a = 0.f;
        for (int m = 0; m < 64; ++m) a = fmaf(b1[m], w2l[m * 16 + j], a);
        cbuf[j] = a;
    } else if (j < 32) {
        const int jj = j - 16;
        float a = 0.f;
        for (int m = 0; m < 64; ++m) a = fmaf(b1[m], w2r[m * 16 + jj], a);
        cbuf[j] = a;
    } else if (j < 48) {
        const int k = j - 32;
        float a = 0.f;
        for (int m = 0; m < 8; ++m) a = fmaf(fc1w[k * 8 + m], fc2w[m], a);
        cbuf[j] = a;
    } else if (j == 48) {
        float a = fc2b[0];
        for (int m = 0; m < 8; ++m) a = fmaf(fc1b[m], fc2w[m], a);
        cbuf[48] = a;
    }
}

// ---- y = x @ A;  p = y[:,0:32], q = y[:,32:64]
__global__ __launch_bounds__(256) void gemm_pq(const float* __restrict__ x,
    const float* __restrict__ A, float* __restrict__ p, float* __restrict__ q)
{
    __shared__ float sA[128 * 64];
    __shared__ float sx[32 * 128];
    const int tid = threadIdx.x;
    for (int i = tid; i < 128 * 64; i += 256) sA[i] = A[i];
    const int base = blockIdx.x * 32;
    const float* xb = x + (size_t)base * 128;
    for (int i = tid; i < 32 * 128; i += 256) sx[i] = xb[i];
    __syncthreads();

    const int j = tid & 63;
    const int nslot = tid >> 6;
    for (int ns = 0; ns < 8; ++ns) {
        const int node = ns * 4 + nslot;
        const float* xr = &sx[node * 128];
        float acc = 0.f;
#pragma unroll 8
        for (int k = 0; k < 128; ++k) acc = fmaf(xr[k], sA[k * 64 + j], acc);
        const int gn = base + node;
        if (j < 32) p[(size_t)gn * 32 + j] = acc;
        else        q[(size_t)gn * 32 + (j - 32)] = acc;
    }
}

// ============ CSR build ============
__global__ __launch_bounds__(256) void hist(const int* __restrict__ dst, int* __restrict__ degi)
{
    const int e = blockIdx.x * 256 + threadIdx.x;
    if (e < NE) atomicAdd(&degi[dst[e]], 1);
}

__global__ __launch_bounds__(SCAN_BLK) void scan_part(const int* __restrict__ degi,
    int* __restrict__ rowptr, int* __restrict__ bsum)
{
    __shared__ int s[SCAN_BLK];
    const int gid = blockIdx.x * SCAN_BLK + threadIdx.x;
    const int v = (gid < NN) ? degi[gid] : 0;
    s[threadIdx.x] = v;
    __syncthreads();
    for (int off = 1; off < SCAN_BLK; off <<= 1) {
        const int t = (threadIdx.x >= off) ? s[threadIdx.x - off] : 0;
        __syncthreads();
        s[threadIdx.x] += t;
        __syncthreads();
    }
    if (gid < NN) rowptr[gid] = s[threadIdx.x] - v;   // exclusive
    if (threadIdx.x == SCAN_BLK - 1) bsum[blockIdx.x] = s[SCAN_BLK - 1];
}

__global__ void scan_top(const int* __restrict__ bsum, int* __restrict__ boff)
{
    if (threadIdx.x == 0) {
        int acc = 0;
        for (int i = 0; i < NSCAN; ++i) { boff[i] = acc; acc += bsum[i]; }
    }
}

__global__ __launch_bounds__(256) void scan_add(int* __restrict__ rowptr,
    const int* __restrict__ boff, int* __restrict__ cursor)
{
    const int gid = blockIdx.x * 256 + threadIdx.x;
    if (gid < NN) {
        const int r = rowptr[gid] + boff[gid >> 10];
        rowptr[gid] = r;
        cursor[gid] = r;
    }
    if (gid == 0) rowptr[NN] = NE;
}

__global__ __launch_bounds__(256) void scatter_csr(const int* __restrict__ src,
    const int* __restrict__ dst, int* __restrict__ cursor, int* __restrict__ cols)
{
    const int e = blockIdx.x * 256 + threadIdx.x;
    if (e >= NE) return;
    const int pos = atomicAdd(&cursor[dst[e]], 1);
    cols[pos] = src[e];
}

// ============ aggregation via CSR (no fp atomics) ============
// layer 1: 32 lanes per node; g = sum(p_l)/deg + q_l + cl ; r = sum(p_r)/deg + q_r + cr
__global__ __launch_bounds__(256) void agg1_csr(const int* __restrict__ rowptr,
    const int* __restrict__ cols, const float* __restrict__ p,
    const float* __restrict__ q, const float* __restrict__ cbuf,
    float* __restrict__ g, float* __restrict__ r)
{
    const int node = blockIdx.x * 8 + (threadIdx.x >> 5);
    if (node >= NN) return;
    const int f = threadIdx.x & 31;
    const int beg = rowptr[node], end = rowptr[node + 1];
    float acc = 0.f;
    int j = beg;
    for (; j + 1 < end; j += 2) {
        const int s0 = cols[j], s1 = cols[j + 1];
        const float v0 = p[(size_t)s0 * 32 + f];
        const float v1 = p[(size_t)s1 * 32 + f];
        acc += v0 + v1;
    }
    if (j < end) acc += p[(size_t)cols[j] * 32 + f];
    const float dg = (float)(end - beg);
    const float m = acc * (1.0f / fmaxf(dg, 1.0f));
    const float val = m + q[(size_t)node * 32 + f] + cbuf[f];
    if (f < 16) g[(size_t)node * 16 + f] = val;
    else        r[(size_t)node * 16 + (f - 16)] = val;
}

// layer 2: 16 lanes per node; h2 = sum(g)/deg + r + b2
__global__ __launch_bounds__(256) void agg2_csr(const int* __restrict__ rowptr,
    const int* __restrict__ cols, const float* __restrict__ g,
    const float* __restrict__ r, const float* __restrict__ b2,
    float* __restrict__ h2)
{
    const int node = blockIdx.x * 16 + (threadIdx.x >> 4);
    if (node >= NN) return;
    const int f = threadIdx.x & 15;
    const int beg = rowptr[node], end = rowptr[node + 1];
    float acc = 0.f;
    int j = beg;
    for (; j + 1 < end; j += 2) {
        const int s0 = cols[j], s1 = cols[j + 1];
        const float v0 = g[(size_t)s0 * 16 + f];
        const float v1 = g[(size_t)s1 * 16 + f];
        acc += v0 + v1;
    }
    if (j < end) acc += g[(size_t)cols[j] * 16 + f];
    const float dg = (float)(end - beg);
    h2[(size_t)node * 16 + f] = acc * (1.0f / fmaxf(dg, 1.0f))
                              + r[(size_t)node * 16 + f] + b2[f];
}

// ---- out = sigmoid( sum_k h2[s][k]*h2[d][k]*v[k] + c )
__global__ __launch_bounds__(256) void edge_mlp(const int* __restrict__ src,
    const int* __restrict__ dst, const float* __restrict__ h2,
    const float* __restrict__ cbuf, float* __restrict__ out)
{
    __shared__ float sv[17];
    if (threadIdx.x < 16) sv[threadIdx.x] = cbuf[32 + threadIdx.x];
    if (threadIdx.x == 16) sv[16] = cbuf[48];
    __syncthreads();
    const int e = blockIdx.x * 256 + threadIdx.x;
    if (e >= NE) return;
    const int s = src[e], d = dst[e];
    const float4* hs = (const float4*)(h2 + (size_t)s * 16);
    const float4* hd = (const float4*)(h2 + (size_t)d * 16);
    float acc = sv[16];
#pragma unroll
    for (int qq = 0; qq < 4; ++qq) {
        const float4 a = hs[qq], b = hd[qq];
        acc = fmaf(a.x * b.x, sv[qq * 4 + 0], acc);
        acc = fmaf(a.y * b.y, sv[qq * 4 + 1], acc);
        acc = fmaf(a.z * b.z, sv[qq * 4 + 2], acc);
        acc = fmaf(a.w * b.w, sv[qq * 4 + 3], acc);
    }
    out[e] = 1.0f / (1.0f + __expf(-acc));
}

extern "C" void kernel_launch(void* const* d_in, const int* in_sizes, int n_in,
                              void* d_out, int out_size, void* d_ws, size_t ws_size,
                              hipStream_t stream)
{
    const float* x    = (const float*)d_in[0];
    const int*   ei   = (const int*)d_in[1];
    const float* w1l  = (const float*)d_in[2];
    const float* w1r  = (const float*)d_in[3];
    const float* b1   = (const float*)d_in[4];
    const float* w2l  = (const float*)d_in[5];
    const float* w2r  = (const float*)d_in[6];
    const float* b2   = (const float*)d_in[7];
    const float* fc1w = (const float*)d_in[8];
    const float* fc1b = (const float*)d_in[9];
    const float* fc2w = (const float*)d_in[10];
    const float* fc2b = (const float*)d_in[11];
    float* out = (float*)d_out;

    const int* src = ei;
    const int* dst = ei + NE;

    // workspace layout
    float* ws   = (float*)d_ws;
    float* A    = ws;                       // 8192 f
    float* cbuf = ws + 8192;                // 64 f
    int* degi   = (int*)(ws + 8256);        // NN
    int* rowptr = degi + NN;                // NN+4 (rowptr[NN] used)
    int* cursor = rowptr + NN + 4;          // NN
    int* bsum   = cursor + NN;              // 128
    int* boff   = bsum + 128;               // 128
    int* cols   = boff + 128;               // NE
    float* p    = (float*)(cols + NE);      // NN*32
    float* q    = p + (size_t)NN * 32;      // NN*32
    float* g    = q + (size_t)NN * 32;      // NN*16
    float* r    = g + (size_t)NN * 16;      // NN*16
    float* h2   = r + (size_t)NN * 16;      // NN*16

    hipMemsetAsync(degi, 0, (size_t)NN * sizeof(int), stream);

    precomp_A<<<128, 64, 0, stream>>>(w1l, w1r, w2l, w2r, A);
    precomp_consts<<<1, 64, 0, stream>>>(b1, w2l, w2r, fc1w, fc1b, fc2w, fc2b, cbuf);

    // CSR build (int atomics only)
    hist<<<NE / 256, 256, 0, stream>>>(dst, degi);
    scan_part<<<NSCAN, SCAN_BLK, 0, stream>>>(degi, rowptr, bsum);
    scan_top<<<1, 64, 0, stream>>>(bsum, boff);
    scan_add<<<(NN + 255) / 256, 256, 0, stream>>>(rowptr, boff, cursor);
    scatter_csr<<<NE / 256, 256, 0, stream>>>(src, dst, cursor, cols);

    // dense projection
    gemm_pq<<<NN / 32, 256, 0, stream>>>(x, A, p, q);

    // aggregations (gather, no fp atomics)
    agg1_csr<<<(NN + 7) / 8, 256, 0, stream>>>(rowptr, cols, p, q, cbuf, g, r);
    agg2_csr<<<(NN + 15) / 16, 256, 0, stream>>>(rowptr, cols, g, r, b2, h2);

    // head
    edge_mlp<<<NE / 256, 256, 0, stream>>>(src, dst, h2, cbuf, out);
}

// Round 4
// 312.613 us; speedup vs baseline: 2.3753x; 1.4057x over previous
//
#include <hip/hip_runtime.h>
#include <math.h>

#define NN 100000
#define NE 1600000

#define NB   196        // buckets = ceil(NN/512); bucket = dst >> 9
#define BKN  512        // nodes per bucket
#define ABLK 128        // partition blocks
#define EPB  ((NE + ABLK - 1) / ABLK)   // 12500 edges per partition block

// ---- A[128][64] = [w1l@w2l | w1l@w2r | w1r@w2l | w1r@w2r]
__global__ __launch_bounds__(64) void precomp_A(const float* __restrict__ w1l,
    const float* __restrict__ w1r, const float* __restrict__ w2l,
    const float* __restrict__ w2r, float* __restrict__ A)
{
    __shared__ float sl[64], sr[64];
    const int k = blockIdx.x;
    const int j = threadIdx.x;
    sl[j] = w1l[k * 64 + j];
    sr[j] = w1r[k * 64 + j];
    __syncthreads();
    const int sel = j >> 4, jj = j & 15;
    const float* row = (sel < 2) ? sl : sr;
    const float* w2  = (sel & 1) ? w2r : w2l;
    float acc = 0.f;
#pragma unroll
    for (int m = 0; m < 64; ++m) acc = fmaf(row[m], w2[m * 16 + jj], acc);
    A[k * 64 + j] = acc;
}

// ---- cbuf: [0:16)=b1@w2l  [16:32)=b1@w2r  [32:48)=v=fc1w@fc2w  [48]=c
__global__ void precomp_consts(const float* __restrict__ b1,
    const float* __restrict__ w2l, const float* __restrict__ w2r,
    const float* __restrict__ fc1w, const float* __restrict__ fc1b,
    const float* __restrict__ fc2w, const float* __restrict__ fc2b,
    float* __restrict__ cbuf)
{
    const int j = threadIdx.x;
    if (j < 16) {
        float a = 0.f;
        for (int m = 0; m < 64; ++m) a = fmaf(b1[m], w2l[m * 16 + j], a);
        cbuf[j] = a;
    } else if (j < 32) {
        const int jj = j - 16;
        float a = 0.f;
        for (int m = 0; m < 64; ++m) a = fmaf(b1[m], w2r[m * 16 + jj], a);
        cbuf[j] = a;
    } else if (j < 48) {
        const int k = j - 32;
        float a = 0.f;
        for (int m = 0; m < 8; ++m) a = fmaf(fc1w[k * 8 + m], fc2w[m], a);
        cbuf[j] = a;
    } else if (j == 48) {
        float a = fc2b[0];
        for (int m = 0; m < 8; ++m) a = fmaf(fc1b[m], fc2w[m], a);
        cbuf[48] = a;
    }
}

// ---- y = x @ A;  p = y[:,0:32], q = y[:,32:64]
__global__ __launch_bounds__(256) void gemm_pq(const float* __restrict__ x,
    const float* __restrict__ A, float* __restrict__ p, float* __restrict__ q)
{
    __shared__ float sA[128 * 64];
    __shared__ float sx[32 * 128];
    const int tid = threadIdx.x;
    for (int i = tid; i < 128 * 64; i += 256) sA[i] = A[i];
    const int base = blockIdx.x * 32;
    const float* xb = x + (size_t)base * 128;
    for (int i = tid; i < 32 * 128; i += 256) sx[i] = xb[i];
    __syncthreads();

    const int j = tid & 63;
    const int nslot = tid >> 6;
    for (int ns = 0; ns < 8; ++ns) {
        const int node = ns * 4 + nslot;
        const float* xr = &sx[node * 128];
        float acc = 0.f;
#pragma unroll 8
        for (int k = 0; k < 128; ++k) acc = fmaf(xr[k], sA[k * 64 + j], acc);
        const int gn = base + node;
        if (j < 32) p[(size_t)gn * 32 + j] = acc;
        else        q[(size_t)gn * 32 + (j - 32)] = acc;
    }
}

// ============ bucketed CSR build (write-combining friendly) ============
// Pass A1: per-block per-bucket histogram -> mat[a][b]
__global__ __launch_bounds__(256) void partA_count(const int* __restrict__ dst,
    int* __restrict__ mat)
{
    __shared__ int h[NB];
    for (int i = threadIdx.x; i < NB; i += 256) h[i] = 0;
    __syncthreads();
    const int a = blockIdx.x;
    const int beg = a * EPB;
    const int end = (beg + EPB < NE) ? beg + EPB : NE;
    for (int e = beg + threadIdx.x; e < end; e += 256)
        atomicAdd(&h[dst[e] >> 9], 1);
    __syncthreads();
    for (int i = threadIdx.x; i < NB; i += 256) mat[a * NB + i] = h[i];
}

// Pass A2: column-wise exclusive scan of mat + bucket bases (absolute offsets)
__global__ __launch_bounds__(256) void partA_scan(int* __restrict__ mat,
    int* __restrict__ bbase)
{
    __shared__ int tot[NB];
    const int b = threadIdx.x;
    if (b < NB) {
        int run = 0;
        for (int a = 0; a < ABLK; ++a) {
            const int t = mat[a * NB + b];
            mat[a * NB + b] = run;
            run += t;
        }
        tot[b] = run;
    }
    __syncthreads();
    if (threadIdx.x == 0) {
        int acc = 0;
        for (int i = 0; i < NB; ++i) {
            const int t = tot[i];
            tot[i] = acc;
            bbase[i] = acc;
            acc += t;
        }
        bbase[NB] = acc;   // == NE
    }
    __syncthreads();
    if (b < NB) {
        const int base = tot[b];
        for (int a = 0; a < ABLK; ++a) mat[a * NB + b] += base;
    }
}

// Pass A3: scatter (src,dst) into bucket-grouped array; each block writes only
// its own reserved contiguous ranges -> L2 write-combining works.
__global__ __launch_bounds__(256) void partA_scatter(const int* __restrict__ src,
    const int* __restrict__ dst, const int* __restrict__ mat,
    uint2* __restrict__ part)
{
    __shared__ int cur[NB];
    const int a = blockIdx.x;
    for (int i = threadIdx.x; i < NB; i += 256) cur[i] = mat[a * NB + i];
    __syncthreads();
    const int beg = a * EPB;
    const int end = (beg + EPB < NE) ? beg + EPB : NE;
    for (int e = beg + threadIdx.x; e < end; e += 256) {
        const int s = src[e], d = dst[e];
        const int pos = atomicAdd(&cur[d >> 9], 1);
        part[pos] = make_uint2((unsigned)s, (unsigned)d);
    }
}

// Pass B: one block per bucket; LDS histogram over 512 local nodes + scan +
// LDS-cursor scatter. rowptr + cols written into contiguous bucket region.
__global__ __launch_bounds__(512) void partB_build(const uint2* __restrict__ part,
    const int* __restrict__ bbase, int* __restrict__ rowptr, int* __restrict__ cols)
{
    __shared__ int h[BKN];
    __shared__ int cur[BKN];
    const int b = blockIdx.x;
    const int beg = bbase[b], end = bbase[b + 1];
    const int nbase = b * BKN;
    h[threadIdx.x] = 0;
    __syncthreads();
    for (int e = beg + threadIdx.x; e < end; e += 512)
        atomicAdd(&h[part[e].y - nbase], 1);
    __syncthreads();
    const int v = h[threadIdx.x];
    // Hillis-Steele inclusive scan over 512
    for (int off = 1; off < BKN; off <<= 1) {
        const int t = (threadIdx.x >= off) ? h[threadIdx.x - off] : 0;
        __syncthreads();
        h[threadIdx.x] += t;
        __syncthreads();
    }
    const int excl = h[threadIdx.x] - v;
    cur[threadIdx.x] = excl;
    const int node = nbase + threadIdx.x;
    if (node < NN) rowptr[node] = beg + excl;
    if (b == NB - 1 && threadIdx.x == 0) rowptr[NN] = NE;
    __syncthreads();
    for (int e = beg + threadIdx.x; e < end; e += 512) {
        const uint2 ed = part[e];
        const int pos = atomicAdd(&cur[ed.y - nbase], 1);
        cols[beg + pos] = (int)ed.x;
    }
}

// ============ aggregation via CSR (no fp atomics) ============
__global__ __launch_bounds__(256) void agg1_csr(const int* __restrict__ rowptr,
    const int* __restrict__ cols, const float* __restrict__ p,
    const float* __restrict__ q, const float* __restrict__ cbuf,
    float* __restrict__ g, float* __restrict__ r)
{
    const int node = blockIdx.x * 8 + (threadIdx.x >> 5);
    if (node >= NN) return;
    const int f = threadIdx.x & 31;
    const int beg = rowptr[node], end = rowptr[node + 1];
    float acc = 0.f;
    int j = beg;
    for (; j + 1 < end; j += 2) {
        const int s0 = cols[j], s1 = cols[j + 1];
        acc += p[(size_t)s0 * 32 + f] + p[(size_t)s1 * 32 + f];
    }
    if (j < end) acc += p[(size_t)cols[j] * 32 + f];
    const float dg = (float)(end - beg);
    const float m = acc * (1.0f / fmaxf(dg, 1.0f));
    const float val = m + q[(size_t)node * 32 + f] + cbuf[f];
    if (f < 16) g[(size_t)node * 16 + f] = val;
    else        r[(size_t)node * 16 + (f - 16)] = val;
}

__global__ __launch_bounds__(256) void agg2_csr(const int* __restrict__ rowptr,
    const int* __restrict__ cols, const float* __restrict__ g,
    const float* __restrict__ r, const float* __restrict__ b2,
    float* __restrict__ h2)
{
    const int node = blockIdx.x * 16 + (threadIdx.x >> 4);
    if (node >= NN) return;
    const int f = threadIdx.x & 15;
    const int beg = rowptr[node], end = rowptr[node + 1];
    float acc = 0.f;
    int j = beg;
    for (; j + 1 < end; j += 2) {
        const int s0 = cols[j], s1 = cols[j + 1];
        acc += g[(size_t)s0 * 16 + f] + g[(size_t)s1 * 16 + f];
    }
    if (j < end) acc += g[(size_t)cols[j] * 16 + f];
    const float dg = (float)(end - beg);
    h2[(size_t)node * 16 + f] = acc * (1.0f / fmaxf(dg, 1.0f))
                              + r[(size_t)node * 16 + f] + b2[f];
}

// ---- out = sigmoid( sum_k h2[s][k]*h2[d][k]*v[k] + c )
__global__ __launch_bounds__(256) void edge_mlp(const int* __restrict__ src,
    const int* __restrict__ dst, const float* __restrict__ h2,
    const float* __restrict__ cbuf, float* __restrict__ out)
{
    __shared__ float sv[17];
    if (threadIdx.x < 16) sv[threadIdx.x] = cbuf[32 + threadIdx.x];
    if (threadIdx.x == 16) sv[16] = cbuf[48];
    __syncthreads();
    const int e = blockIdx.x * 256 + threadIdx.x;
    if (e >= NE) return;
    const int s = src[e], d = dst[e];
    const float4* hs = (const float4*)(h2 + (size_t)s * 16);
    const float4* hd = (const float4*)(h2 + (size_t)d * 16);
    float acc = sv[16];
#pragma unroll
    for (int qq = 0; qq < 4; ++qq) {
        const float4 a = hs[qq], b = hd[qq];
        acc = fmaf(a.x * b.x, sv[qq * 4 + 0], acc);
        acc = fmaf(a.y * b.y, sv[qq * 4 + 1], acc);
        acc = fmaf(a.z * b.z, sv[qq * 4 + 2], acc);
        acc = fmaf(a.w * b.w, sv[qq * 4 + 3], acc);
    }
    out[e] = 1.0f / (1.0f + __expf(-acc));
}

extern "C" void kernel_launch(void* const* d_in, const int* in_sizes, int n_in,
                              void* d_out, int out_size, void* d_ws, size_t ws_size,
                              hipStream_t stream)
{
    const float* x    = (const float*)d_in[0];
    const int*   ei   = (const int*)d_in[1];
    const float* w1l  = (const float*)d_in[2];
    const float* w1r  = (const float*)d_in[3];
    const float* b1   = (const float*)d_in[4];
    const float* w2l  = (const float*)d_in[5];
    const float* w2r  = (const float*)d_in[6];
    const float* b2   = (const float*)d_in[7];
    const float* fc1w = (const float*)d_in[8];
    const float* fc1b = (const float*)d_in[9];
    const float* fc2w = (const float*)d_in[10];
    const float* fc2b = (const float*)d_in[11];
    float* out = (float*)d_out;

    const int* src = ei;
    const int* dst = ei + NE;

    // workspace layout (int units, part kept 8B-aligned)
    int* W = (int*)d_ws;
    size_t o = 0;
    int* mat    = W + o; o += (size_t)ABLK * NB;     // 25088
    int* bbase  = W + o; o += NB + 1;                // 197
    int* rowptr = W + o; o += NN + 1;                // 100001
    if (o & 1) ++o;                                  // align part to 8B
    uint2* part = (uint2*)(W + o); o += (size_t)NE * 2;
    int* cols   = W + o; o += NE;
    float* A    = (float*)(W + o); o += 8192;
    float* cbuf = (float*)(W + o); o += 64;
    float* p    = (float*)(W + o); o += (size_t)NN * 32;
    float* q    = (float*)(W + o); o += (size_t)NN * 32;
    float* g    = (float*)(W + o); o += (size_t)NN * 16;
    float* r    = (float*)(W + o); o += (size_t)NN * 16;
    float* h2   = (float*)(W + o); o += (size_t)NN * 16;

    precomp_A<<<128, 64, 0, stream>>>(w1l, w1r, w2l, w2r, A);
    precomp_consts<<<1, 64, 0, stream>>>(b1, w2l, w2r, fc1w, fc1b, fc2w, fc2b, cbuf);

    // bucketed CSR build
    partA_count<<<ABLK, 256, 0, stream>>>(dst, mat);
    partA_scan<<<1, 256, 0, stream>>>(mat, bbase);
    partA_scatter<<<ABLK, 256, 0, stream>>>(src, dst, mat, part);
    partB_build<<<NB, 512, 0, stream>>>(part, bbase, rowptr, cols);

    // dense projection
    gemm_pq<<<NN / 32, 256, 0, stream>>>(x, A, p, q);

    // aggregations (gather, no fp atomics)
    agg1_csr<<<(NN + 7) / 8, 256, 0, stream>>>(rowptr, cols, p, q, cbuf, g, r);
    agg2_csr<<<(NN + 15) / 16, 256, 0, stream>>>(rowptr, cols, g, r, b2, h2);

    // head
    edge_mlp<<<NE / 256, 256, 0, stream>>>(src, dst, h2, cbuf, out);
}

// Round 5
// 248.663 us; speedup vs baseline: 2.9861x; 1.2572x over previous
//
#include <hip/hip_runtime.h>
#include <math.h>

#define NN 100000
#define NE 1600000

#define NB   196        // buckets = ceil(NN/512); bucket = dst >> 9
#define BKN  512        // nodes per bucket
#define ABLK 128        // partition blocks
#define EPB  ((NE + ABLK - 1) / ABLK)   // 12500 edges per partition block

typedef __attribute__((ext_vector_type(8))) short bf16x8;
typedef __attribute__((ext_vector_type(4))) float f32x4;

__device__ __forceinline__ unsigned short f2bf(float f) {
    unsigned u = __builtin_bit_cast(unsigned, f);
    u += 0x7fffu + ((u >> 16) & 1u);           // RNE
    return (unsigned short)(u >> 16);
}
__device__ __forceinline__ float bf2f(unsigned short h) {
    unsigned u = ((unsigned)h) << 16;
    return __builtin_bit_cast(float, u);
}

// ---- A[128][64] = [w1l@w2l | w1l@w2r | w1r@w2l | w1r@w2r]
__global__ __launch_bounds__(64) void precomp_A(const float* __restrict__ w1l,
    const float* __restrict__ w1r, const float* __restrict__ w2l,
    const float* __restrict__ w2r, float* __restrict__ A)
{
    __shared__ float sl[64], sr[64];
    const int k = blockIdx.x;
    const int j = threadIdx.x;
    sl[j] = w1l[k * 64 + j];
    sr[j] = w1r[k * 64 + j];
    __syncthreads();
    const int sel = j >> 4, jj = j & 15;
    const float* row = (sel < 2) ? sl : sr;
    const float* w2  = (sel & 1) ? w2r : w2l;
    float acc = 0.f;
#pragma unroll
    for (int m = 0; m < 64; ++m) acc = fmaf(row[m], w2[m * 16 + jj], acc);
    A[k * 64 + j] = acc;
}

// ---- AT (transposed, bf16 hi/lo): ATh/ATl[col][k], col<64, k<128
__global__ __launch_bounds__(256) void convA(const float* __restrict__ A,
    unsigned short* __restrict__ ATh, unsigned short* __restrict__ ATl)
{
    const int i = blockIdx.x * 256 + threadIdx.x;
    if (i >= 8192) return;
    const int col = i >> 7, k = i & 127;
    const float v = A[k * 64 + col];
    const unsigned short h = f2bf(v);
    ATh[col * 128 + k] = h;
    ATl[col * 128 + k] = f2bf(v - bf2f(h));
}

// ---- cbuf: [0:16)=b1@w2l  [16:32)=b1@w2r  [32:48)=v=fc1w@fc2w  [48]=c
__global__ void precomp_consts(const float* __restrict__ b1,
    const float* __restrict__ w2l, const float* __restrict__ w2r,
    const float* __restrict__ fc1w, const float* __restrict__ fc1b,
    const float* __restrict__ fc2w, const float* __restrict__ fc2b,
    float* __restrict__ cbuf)
{
    const int j = threadIdx.x;
    if (j < 16) {
        float a = 0.f;
        for (int m = 0; m < 64; ++m) a = fmaf(b1[m], w2l[m * 16 + j], a);
        cbuf[j] = a;
    } else if (j < 32) {
        const int jj = j - 16;
        float a = 0.f;
        for (int m = 0; m < 64; ++m) a = fmaf(b1[m], w2r[m * 16 + jj], a);
        cbuf[j] = a;
    } else if (j < 48) {
        const int k = j - 32;
        float a = 0.f;
        for (int m = 0; m < 8; ++m) a = fmaf(fc1w[k * 8 + m], fc2w[m], a);
        cbuf[j] = a;
    } else if (j == 48) {
        float a = fc2b[0];
        for (int m = 0; m < 8; ++m) a = fmaf(fc1b[m], fc2w[m], a);
        cbuf[48] = a;
    }
}

// ---- MFMA GEMM: y = x @ A via bf16 split (xh@Ah + xh@Al + xl@Ah)
//      p = y[:,0:32], q = y[:,32:64]
#define LDST 136   // padded LDS row stride in bf16 elems (128 + 8)
__global__ __launch_bounds__(256) void gemm_mfma(const float* __restrict__ x,
    const unsigned short* __restrict__ ATh, const unsigned short* __restrict__ ATl,
    float* __restrict__ p, float* __restrict__ q)
{
    __shared__ unsigned short sAh[64 * LDST];
    __shared__ unsigned short sAl[64 * LDST];
    const int tid = threadIdx.x;
    for (int i = tid; i < 1024; i += 256) {          // 64 rows x 16 chunks of 8 bf16
        const int row = i >> 4, ch = i & 15;
        const uint4 vh = *(const uint4*)(ATh + row * 128 + ch * 8);
        const uint4 vl = *(const uint4*)(ATl + row * 128 + ch * 8);
        *(uint4*)(sAh + row * LDST + ch * 8) = vh;
        *(uint4*)(sAl + row * LDST + ch * 8) = vl;
    }
    __syncthreads();

    const int wave = tid >> 6;
    const int lane = tid & 63;
    const int lr = lane & 15;       // A-row / B-col / D-col within 16
    const int lg = lane >> 4;       // k-group (8 elems)

    // B fragments in registers: [coltile][kstep], hi and lo
    bf16x8 bh[4][4], bl[4][4];
#pragma unroll
    for (int ct = 0; ct < 4; ++ct) {
        const int col = ct * 16 + lr;
#pragma unroll
        for (int ks = 0; ks < 4; ++ks) {
            const int k0 = ks * 32 + lg * 8;
            bh[ct][ks] = *(const bf16x8*)(sAh + col * LDST + k0);
            bl[ct][ks] = *(const bf16x8*)(sAl + col * LDST + k0);
        }
    }

    const int tilebase = blockIdx.x * 64;
    const int xrowidx = tilebase + wave * 16 + lr;
    const float* xrow = x + (size_t)(xrowidx < NN ? xrowidx : NN - 1) * 128;

    f32x4 acc[4] = {f32x4{0,0,0,0}, f32x4{0,0,0,0}, f32x4{0,0,0,0}, f32x4{0,0,0,0}};
#pragma unroll
    for (int ks = 0; ks < 4; ++ks) {
        const int k0 = ks * 32 + lg * 8;
        const float4 v0 = *(const float4*)(xrow + k0);
        const float4 v1 = *(const float4*)(xrow + k0 + 4);
        const float vv[8] = {v0.x, v0.y, v0.z, v0.w, v1.x, v1.y, v1.z, v1.w};
        bf16x8 xh, xl;
#pragma unroll
        for (int j = 0; j < 8; ++j) {
            const unsigned short h = f2bf(vv[j]);
            xh[j] = (short)h;
            xl[j] = (short)f2bf(vv[j] - bf2f(h));
        }
#pragma unroll
        for (int ct = 0; ct < 4; ++ct) {
            acc[ct] = __builtin_amdgcn_mfma_f32_16x16x32_bf16(xh, bh[ct][ks], acc[ct], 0, 0, 0);
            acc[ct] = __builtin_amdgcn_mfma_f32_16x16x32_bf16(xh, bl[ct][ks], acc[ct], 0, 0, 0);
            acc[ct] = __builtin_amdgcn_mfma_f32_16x16x32_bf16(xl, bh[ct][ks], acc[ct], 0, 0, 0);
        }
    }

    // D layout: col = lane&15 (within ct*16), row-within-16 = lg*4 + reg
#pragma unroll
    for (int ct = 0; ct < 4; ++ct) {
        const int col = ct * 16 + lr;
#pragma unroll
        for (int rg = 0; rg < 4; ++rg) {
            const int nrow = tilebase + wave * 16 + lg * 4 + rg;
            if (nrow < NN) {
                if (col < 32) p[(size_t)nrow * 32 + col] = acc[ct][rg];
                else          q[(size_t)nrow * 32 + (col - 32)] = acc[ct][rg];
            }
        }
    }
}

// ============ bucketed CSR build (write-combining friendly) ============
__global__ __launch_bounds__(256) void partA_count(const int* __restrict__ dst,
    int* __restrict__ mat)
{
    __shared__ int h[NB];
    for (int i = threadIdx.x; i < NB; i += 256) h[i] = 0;
    __syncthreads();
    const int a = blockIdx.x;
    const int beg = a * EPB;
    const int end = (beg + EPB < NE) ? beg + EPB : NE;
    for (int e = beg + threadIdx.x; e < end; e += 256)
        atomicAdd(&h[dst[e] >> 9], 1);
    __syncthreads();
    for (int i = threadIdx.x; i < NB; i += 256) mat[a * NB + i] = h[i];
}

__global__ __launch_bounds__(256) void partA_scan(int* __restrict__ mat,
    int* __restrict__ bbase)
{
    __shared__ int tot[NB];
    const int b = threadIdx.x;
    if (b < NB) {
        int run = 0;
        for (int a = 0; a < ABLK; ++a) {
            const int t = mat[a * NB + b];
            mat[a * NB + b] = run;
            run += t;
        }
        tot[b] = run;
    }
    __syncthreads();
    if (threadIdx.x == 0) {
        int acc = 0;
        for (int i = 0; i < NB; ++i) {
            const int t = tot[i];
            tot[i] = acc;
            bbase[i] = acc;
            acc += t;
        }
        bbase[NB] = acc;
    }
    __syncthreads();
    if (b < NB) {
        const int base = tot[b];
        for (int a = 0; a < ABLK; ++a) mat[a * NB + b] += base;
    }
}

__global__ __launch_bounds__(256) void partA_scatter(const int* __restrict__ src,
    const int* __restrict__ dst, const int* __restrict__ mat,
    uint2* __restrict__ part)
{
    __shared__ int cur[NB];
    const int a = blockIdx.x;
    for (int i = threadIdx.x; i < NB; i += 256) cur[i] = mat[a * NB + i];
    __syncthreads();
    const int beg = a * EPB;
    const int end = (beg + EPB < NE) ? beg + EPB : NE;
    for (int e = beg + threadIdx.x; e < end; e += 256) {
        const int s = src[e], d = dst[e];
        const int pos = atomicAdd(&cur[d >> 9], 1);
        part[pos] = make_uint2((unsigned)s, (unsigned)d);
    }
}

__global__ __launch_bounds__(512) void partB_build(const uint2* __restrict__ part,
    const int* __restrict__ bbase, int* __restrict__ rowptr, int* __restrict__ cols)
{
    __shared__ int h[BKN];
    __shared__ int cur[BKN];
    const int b = blockIdx.x;
    const int beg = bbase[b], end = bbase[b + 1];
    const int nbase = b * BKN;
    h[threadIdx.x] = 0;
    __syncthreads();
    for (int e = beg + threadIdx.x; e < end; e += 512)
        atomicAdd(&h[part[e].y - nbase], 1);
    __syncthreads();
    const int v = h[threadIdx.x];
    for (int off = 1; off < BKN; off <<= 1) {
        const int t = (threadIdx.x >= off) ? h[threadIdx.x - off] : 0;
        __syncthreads();
        h[threadIdx.x] += t;
        __syncthreads();
    }
    const int excl = h[threadIdx.x] - v;
    cur[threadIdx.x] = excl;
    const int node = nbase + threadIdx.x;
    if (node < NN) rowptr[node] = beg + excl;
    if (b == NB - 1 && threadIdx.x == 0) rowptr[NN] = NE;
    __syncthreads();
    for (int e = beg + threadIdx.x; e < end; e += 512) {
        const uint2 ed = part[e];
        const int pos = atomicAdd(&cur[ed.y - nbase], 1);
        cols[beg + pos] = (int)ed.x;
    }
}

// ============ aggregation via CSR (no fp atomics) ============
__global__ __launch_bounds__(256) void agg1_csr(const int* __restrict__ rowptr,
    const int* __restrict__ cols, const float* __restrict__ p,
    const float* __restrict__ q, const float* __restrict__ cbuf,
    float* __restrict__ g, float* __restrict__ r)
{
    const int node = blockIdx.x * 8 + (threadIdx.x >> 5);
    if (node >= NN) return;
    const int f = threadIdx.x & 31;
    const int beg = rowptr[node], end = rowptr[node + 1];
    float acc = 0.f;
    int j = beg;
    for (; j + 1 < end; j += 2) {
        const int s0 = cols[j], s1 = cols[j + 1];
        acc += p[(size_t)s0 * 32 + f] + p[(size_t)s1 * 32 + f];
    }
    if (j < end) acc += p[(size_t)cols[j] * 32 + f];
    const float dg = (float)(end - beg);
    const float m = acc * (1.0f / fmaxf(dg, 1.0f));
    const float val = m + q[(size_t)node * 32 + f] + cbuf[f];
    if (f < 16) g[(size_t)node * 16 + f] = val;
    else        r[(size_t)node * 16 + (f - 16)] = val;
}

__global__ __launch_bounds__(256) void agg2_csr(const int* __restrict__ rowptr,
    const int* __restrict__ cols, const float* __restrict__ g,
    const float* __restrict__ r, const float* __restrict__ b2,
    float* __restrict__ h2)
{
    const int node = blockIdx.x * 16 + (threadIdx.x >> 4);
    if (node >= NN) return;
    const int f = threadIdx.x & 15;
    const int beg = rowptr[node], end = rowptr[node + 1];
    float acc = 0.f;
    int j = beg;
    for (; j + 1 < end; j += 2) {
        const int s0 = cols[j], s1 = cols[j + 1];
        acc += g[(size_t)s0 * 16 + f] + g[(size_t)s1 * 16 + f];
    }
    if (j < end) acc += g[(size_t)cols[j] * 16 + f];
    const float dg = (float)(end - beg);
    h2[(size_t)node * 16 + f] = acc * (1.0f / fmaxf(dg, 1.0f))
                              + r[(size_t)node * 16 + f] + b2[f];
}

// ---- out = sigmoid( sum_k h2[s][k]*h2[d][k]*v[k] + c )
__global__ __launch_bounds__(256) void edge_mlp(const int* __restrict__ src,
    const int* __restrict__ dst, const float* __restrict__ h2,
    const float* __restrict__ cbuf, float* __restrict__ out)
{
    __shared__ float sv[17];
    if (threadIdx.x < 16) sv[threadIdx.x] = cbuf[32 + threadIdx.x];
    if (threadIdx.x == 16) sv[16] = cbuf[48];
    __syncthreads();
    const int e = blockIdx.x * 256 + threadIdx.x;
    if (e >= NE) return;
    const int s = src[e], d = dst[e];
    const float4* hs = (const float4*)(h2 + (size_t)s * 16);
    const float4* hd = (const float4*)(h2 + (size_t)d * 16);
    float acc = sv[16];
#pragma unroll
    for (int qq = 0; qq < 4; ++qq) {
        const float4 a = hs[qq], b = hd[qq];
        acc = fmaf(a.x * b.x, sv[qq * 4 + 0], acc);
        acc = fmaf(a.y * b.y, sv[qq * 4 + 1], acc);
        acc = fmaf(a.z * b.z, sv[qq * 4 + 2], acc);
        acc = fmaf(a.w * b.w, sv[qq * 4 + 3], acc);
    }
    out[e] = 1.0f / (1.0f + __expf(-acc));
}

extern "C" void kernel_launch(void* const* d_in, const int* in_sizes, int n_in,
                              void* d_out, int out_size, void* d_ws, size_t ws_size,
                              hipStream_t stream)
{
    const float* x    = (const float*)d_in[0];
    const int*   ei   = (const int*)d_in[1];
    const float* w1l  = (const float*)d_in[2];
    const float* w1r  = (const float*)d_in[3];
    const float* b1   = (const float*)d_in[4];
    const float* w2l  = (const float*)d_in[5];
    const float* w2r  = (const float*)d_in[6];
    const float* b2   = (const float*)d_in[7];
    const float* fc1w = (const float*)d_in[8];
    const float* fc1b = (const float*)d_in[9];
    const float* fc2w = (const float*)d_in[10];
    const float* fc2b = (const float*)d_in[11];
    float* out = (float*)d_out;

    const int* src = ei;
    const int* dst = ei + NE;

    // workspace layout (int units, part kept 8B-aligned)
    int* W = (int*)d_ws;
    size_t o = 0;
    int* mat    = W + o; o += (size_t)ABLK * NB;
    int* bbase  = W + o; o += NB + 1;
    int* rowptr = W + o; o += NN + 1;
    if (o & 1) ++o;
    uint2* part = (uint2*)(W + o); o += (size_t)NE * 2;
    int* cols   = W + o; o += NE;
    float* A    = (float*)(W + o); o += 8192;
    unsigned short* ATh = (unsigned short*)(W + o); o += 4096;  // 8192 bf16
    unsigned short* ATl = (unsigned short*)(W + o); o += 4096;
    float* cbuf = (float*)(W + o); o += 64;
    float* p    = (float*)(W + o); o += (size_t)NN * 32;
    float* q    = (float*)(W + o); o += (size_t)NN * 32;
    float* g    = (float*)(W + o); o += (size_t)NN * 16;
    float* r    = (float*)(W + o); o += (size_t)NN * 16;
    float* h2   = (float*)(W + o); o += (size_t)NN * 16;

    precomp_A<<<128, 64, 0, stream>>>(w1l, w1r, w2l, w2r, A);
    convA<<<32, 256, 0, stream>>>(A, ATh, ATl);
    precomp_consts<<<1, 64, 0, stream>>>(b1, w2l, w2r, fc1w, fc1b, fc2w, fc2b, cbuf);

    // bucketed CSR build
    partA_count<<<ABLK, 256, 0, stream>>>(dst, mat);
    partA_scan<<<1, 256, 0, stream>>>(mat, bbase);
    partA_scatter<<<ABLK, 256, 0, stream>>>(src, dst, mat, part);
    partB_build<<<NB, 512, 0, stream>>>(part, bbase, rowptr, cols);

    // dense projection (MFMA)
    gemm_mfma<<<(NN + 63) / 64, 256, 0, stream>>>(x, ATh, ATl, p, q);

    // aggregations (gather, no fp atomics)
    agg1_csr<<<(NN + 7) / 8, 256, 0, stream>>>(rowptr, cols, p, q, cbuf, g, r);
    agg2_csr<<<(NN + 15) / 16, 256, 0, stream>>>(rowptr, cols, g, r, b2, h2);

    // head
    edge_mlp<<<NE / 256, 256, 0, stream>>>(src, dst, h2, cbuf, out);
}

// Round 6
// 207.693 us; speedup vs baseline: 3.5751x; 1.1973x over previous
//
#include <hip/hip_runtime.h>
#include <hip/hip_fp16.h>
#include <math.h>

#define NN 100000
#define NE 1600000

#define NB   196        // buckets = ceil(NN/512); bucket = dst >> 9
#define BKN  512        // nodes per bucket
#define ABLK 128        // partition blocks
#define EPB  ((NE + ABLK - 1) / ABLK)   // 12500 edges per partition block

typedef __attribute__((ext_vector_type(8))) short bf16x8;
typedef __attribute__((ext_vector_type(4))) float f32x4;

__device__ __forceinline__ unsigned short f2bf(float f) {
    unsigned u = __builtin_bit_cast(unsigned, f);
    u += 0x7fffu + ((u >> 16) & 1u);           // RNE
    return (unsigned short)(u >> 16);
}
__device__ __forceinline__ float bf2f(unsigned short h) {
    unsigned u = ((unsigned)h) << 16;
    return __builtin_bit_cast(float, u);
}
__device__ __forceinline__ float2 unpackh2(unsigned w) {
    const __half2 h = __builtin_bit_cast(__half2, w);
    return __half22float2(h);
}

// ---- A[128][64] = [w1l@w2l | w1l@w2r | w1r@w2l | w1r@w2r]
__global__ __launch_bounds__(64) void precomp_A(const float* __restrict__ w1l,
    const float* __restrict__ w1r, const float* __restrict__ w2l,
    const float* __restrict__ w2r, float* __restrict__ A)
{
    __shared__ float sl[64], sr[64];
    const int k = blockIdx.x;
    const int j = threadIdx.x;
    sl[j] = w1l[k * 64 + j];
    sr[j] = w1r[k * 64 + j];
    __syncthreads();
    const int sel = j >> 4, jj = j & 15;
    const float* row = (sel < 2) ? sl : sr;
    const float* w2  = (sel & 1) ? w2r : w2l;
    float acc = 0.f;
#pragma unroll
    for (int m = 0; m < 64; ++m) acc = fmaf(row[m], w2[m * 16 + jj], acc);
    A[k * 64 + j] = acc;
}

// ---- AT (transposed, bf16 hi/lo): ATh/ATl[col][k]
__global__ __launch_bounds__(256) void convA(const float* __restrict__ A,
    unsigned short* __restrict__ ATh, unsigned short* __restrict__ ATl)
{
    const int i = blockIdx.x * 256 + threadIdx.x;
    if (i >= 8192) return;
    const int col = i >> 7, k = i & 127;
    const float v = A[k * 64 + col];
    const unsigned short h = f2bf(v);
    ATh[col * 128 + k] = h;
    ATl[col * 128 + k] = f2bf(v - bf2f(h));
}

// ---- cbuf: [0:16)=b1@w2l  [16:32)=b1@w2r  [32:48)=v=fc1w@fc2w  [48]=c
__global__ void precomp_consts(const float* __restrict__ b1,
    const float* __restrict__ w2l, const float* __restrict__ w2r,
    const float* __restrict__ fc1w, const float* __restrict__ fc1b,
    const float* __restrict__ fc2w, const float* __restrict__ fc2b,
    float* __restrict__ cbuf)
{
    const int j = threadIdx.x;
    if (j < 16) {
        float a = 0.f;
        for (int m = 0; m < 64; ++m) a = fmaf(b1[m], w2l[m * 16 + j], a);
        cbuf[j] = a;
    } else if (j < 32) {
        const int jj = j - 16;
        float a = 0.f;
        for (int m = 0; m < 64; ++m) a = fmaf(b1[m], w2r[m * 16 + jj], a);
        cbuf[j] = a;
    } else if (j < 48) {
        const int k = j - 32;
        float a = 0.f;
        for (int m = 0; m < 8; ++m) a = fmaf(fc1w[k * 8 + m], fc2w[m], a);
        cbuf[j] = a;
    } else if (j == 48) {
        float a = fc2b[0];
        for (int m = 0; m < 8; ++m) a = fmaf(fc1b[m], fc2w[m], a);
        cbuf[48] = a;
    }
}

// ---- MFMA GEMM: y = x @ A (bf16 3-term split). p -> fp16, q -> fp32
#define LDST 136
__global__ __launch_bounds__(256) void gemm_mfma(const float* __restrict__ x,
    const unsigned short* __restrict__ ATh, const unsigned short* __restrict__ ATl,
    __half* __restrict__ p, float* __restrict__ q)
{
    __shared__ unsigned short sAh[64 * LDST];
    __shared__ unsigned short sAl[64 * LDST];
    const int tid = threadIdx.x;
    for (int i = tid; i < 1024; i += 256) {
        const int row = i >> 4, ch = i & 15;
        const uint4 vh = *(const uint4*)(ATh + row * 128 + ch * 8);
        const uint4 vl = *(const uint4*)(ATl + row * 128 + ch * 8);
        *(uint4*)(sAh + row * LDST + ch * 8) = vh;
        *(uint4*)(sAl + row * LDST + ch * 8) = vl;
    }
    __syncthreads();

    const int wave = tid >> 6;
    const int lane = tid & 63;
    const int lr = lane & 15;
    const int lg = lane >> 4;

    bf16x8 bh[4][4], bl[4][4];
#pragma unroll
    for (int ct = 0; ct < 4; ++ct) {
        const int col = ct * 16 + lr;
#pragma unroll
        for (int ks = 0; ks < 4; ++ks) {
            const int k0 = ks * 32 + lg * 8;
            bh[ct][ks] = *(const bf16x8*)(sAh + col * LDST + k0);
            bl[ct][ks] = *(const bf16x8*)(sAl + col * LDST + k0);
        }
    }

    const int tilebase = blockIdx.x * 64;
    const int xrowidx = tilebase + wave * 16 + lr;
    const float* xrow = x + (size_t)(xrowidx < NN ? xrowidx : NN - 1) * 128;

    f32x4 acc[4] = {f32x4{0,0,0,0}, f32x4{0,0,0,0}, f32x4{0,0,0,0}, f32x4{0,0,0,0}};
#pragma unroll
    for (int ks = 0; ks < 4; ++ks) {
        const int k0 = ks * 32 + lg * 8;
        const float4 v0 = *(const float4*)(xrow + k0);
        const float4 v1 = *(const float4*)(xrow + k0 + 4);
        const float vv[8] = {v0.x, v0.y, v0.z, v0.w, v1.x, v1.y, v1.z, v1.w};
        bf16x8 xh, xl;
#pragma unroll
        for (int j = 0; j < 8; ++j) {
            const unsigned short h = f2bf(vv[j]);
            xh[j] = (short)h;
            xl[j] = (short)f2bf(vv[j] - bf2f(h));
        }
#pragma unroll
        for (int ct = 0; ct < 4; ++ct) {
            acc[ct] = __builtin_amdgcn_mfma_f32_16x16x32_bf16(xh, bh[ct][ks], acc[ct], 0, 0, 0);
            acc[ct] = __builtin_amdgcn_mfma_f32_16x16x32_bf16(xh, bl[ct][ks], acc[ct], 0, 0, 0);
            acc[ct] = __builtin_amdgcn_mfma_f32_16x16x32_bf16(xl, bh[ct][ks], acc[ct], 0, 0, 0);
        }
    }

#pragma unroll
    for (int ct = 0; ct < 4; ++ct) {
        const int col = ct * 16 + lr;
#pragma unroll
        for (int rg = 0; rg < 4; ++rg) {
            const int nrow = tilebase + wave * 16 + lg * 4 + rg;
            if (nrow < NN) {
                if (col < 32) p[(size_t)nrow * 32 + col] = __float2half(acc[ct][rg]);
                else          q[(size_t)nrow * 32 + (col - 32)] = acc[ct][rg];
            }
        }
    }
}

// ============ bucketed CSR build ============
__global__ __launch_bounds__(256) void partA_count(const int* __restrict__ dst,
    int* __restrict__ mat)
{
    __shared__ int h[NB];
    for (int i = threadIdx.x; i < NB; i += 256) h[i] = 0;
    __syncthreads();
    const int a = blockIdx.x;
    const int beg = a * EPB;
    const int end = (beg + EPB < NE) ? beg + EPB : NE;
    for (int e = beg + threadIdx.x; e < end; e += 256)
        atomicAdd(&h[dst[e] >> 9], 1);
    __syncthreads();
    for (int i = threadIdx.x; i < NB; i += 256) mat[a * NB + i] = h[i];
}

__global__ __launch_bounds__(256) void partA_scan(int* __restrict__ mat,
    int* __restrict__ bbase)
{
    __shared__ int tot[NB];
    const int b = threadIdx.x;
    if (b < NB) {
        int run = 0;
        for (int a = 0; a < ABLK; ++a) {
            const int t = mat[a * NB + b];
            mat[a * NB + b] = run;
            run += t;
        }
        tot[b] = run;
    }
    __syncthreads();
    if (threadIdx.x == 0) {
        int acc = 0;
        for (int i = 0; i < NB; ++i) {
            const int t = tot[i];
            tot[i] = acc;
            bbase[i] = acc;
            acc += t;
        }
        bbase[NB] = acc;
    }
    __syncthreads();
    if (b < NB) {
        const int base = tot[b];
        for (int a = 0; a < ABLK; ++a) mat[a * NB + b] += base;
    }
}

// packed entry: (src << 9) | local_dst   (src < 2^17, local < 512)
__global__ __launch_bounds__(256) void partA_scatter(const int* __restrict__ src,
    const int* __restrict__ dst, const int* __restrict__ mat,
    unsigned* __restrict__ part)
{
    __shared__ int cur[NB];
    const int a = blockIdx.x;
    for (int i = threadIdx.x; i < NB; i += 256) cur[i] = mat[a * NB + i];
    __syncthreads();
    const int beg = a * EPB;
    const int end = (beg + EPB < NE) ? beg + EPB : NE;
    for (int e = beg + threadIdx.x; e < end; e += 256) {
        const int s = src[e], d = dst[e];
        const int pos = atomicAdd(&cur[d >> 9], 1);
        part[pos] = ((unsigned)s << 9) | (unsigned)(d & 511);
    }
}

__global__ __launch_bounds__(512) void partB_build(const unsigned* __restrict__ part,
    const int* __restrict__ bbase, int* __restrict__ rowptr, int* __restrict__ cols)
{
    __shared__ int h[BKN];
    __shared__ int cur[BKN];
    const int b = blockIdx.x;
    const int beg = bbase[b], end = bbase[b + 1];
    h[threadIdx.x] = 0;
    __syncthreads();
    for (int e = beg + threadIdx.x; e < end; e += 512)
        atomicAdd(&h[part[e] & 511u], 1);
    __syncthreads();
    const int v = h[threadIdx.x];
    for (int off = 1; off < BKN; off <<= 1) {
        const int t = (threadIdx.x >= off) ? h[threadIdx.x - off] : 0;
        __syncthreads();
        h[threadIdx.x] += t;
        __syncthreads();
    }
    const int excl = h[threadIdx.x] - v;
    cur[threadIdx.x] = excl;
    const int node = b * BKN + threadIdx.x;
    if (node < NN) rowptr[node] = beg + excl;
    if (b == NB - 1 && threadIdx.x == 0) rowptr[NN] = NE;
    __syncthreads();
    for (int e = beg + threadIdx.x; e < end; e += 512) {
        const unsigned w = part[e];
        const int pos = atomicAdd(&cur[w & 511u], 1);
        cols[beg + pos] = (int)(w >> 9);
    }
}

// ============ aggregation via CSR (fp16 payloads) ============
__global__ __launch_bounds__(256) void agg1_csr(const int* __restrict__ rowptr,
    const int* __restrict__ cols, const __half* __restrict__ p,
    const float* __restrict__ q, const float* __restrict__ cbuf,
    __half* __restrict__ g, float* __restrict__ r)
{
    const int node = blockIdx.x * 8 + (threadIdx.x >> 5);
    if (node >= NN) return;
    const int f = threadIdx.x & 31;
    const int beg = rowptr[node], end = rowptr[node + 1];
    float acc = 0.f;
    int j = beg;
    for (; j + 1 < end; j += 2) {
        const int s0 = cols[j], s1 = cols[j + 1];
        acc += __half2float(p[(size_t)s0 * 32 + f]) + __half2float(p[(size_t)s1 * 32 + f]);
    }
    if (j < end) acc += __half2float(p[(size_t)cols[j] * 32 + f]);
    const float dg = (float)(end - beg);
    const float m = acc * (1.0f / fmaxf(dg, 1.0f));
    const float val = m + q[(size_t)node * 32 + f] + cbuf[f];
    if (f < 16) g[(size_t)node * 16 + f] = __float2half(val);
    else        r[(size_t)node * 16 + (f - 16)] = val;
}

__global__ __launch_bounds__(256) void agg2_csr(const int* __restrict__ rowptr,
    const int* __restrict__ cols, const __half* __restrict__ g,
    const float* __restrict__ r, const float* __restrict__ b2,
    __half* __restrict__ h2)
{
    const int node = blockIdx.x * 16 + (threadIdx.x >> 4);
    if (node >= NN) return;
    const int f = threadIdx.x & 15;
    const int beg = rowptr[node], end = rowptr[node + 1];
    float acc = 0.f;
    int j = beg;
    for (; j + 1 < end; j += 2) {
        const int s0 = cols[j], s1 = cols[j + 1];
        acc += __half2float(g[(size_t)s0 * 16 + f]) + __half2float(g[(size_t)s1 * 16 + f]);
    }
    if (j < end) acc += __half2float(g[(size_t)cols[j] * 16 + f]);
    const float dg = (float)(end - beg);
    const float val = acc * (1.0f / fmaxf(dg, 1.0f))
                    + r[(size_t)node * 16 + f] + b2[f];
    h2[(size_t)node * 16 + f] = __float2half(val);
}

// ---- out = sigmoid( sum_k h2[s][k]*h2[d][k]*v[k] + c )
__global__ __launch_bounds__(256) void edge_mlp(const int* __restrict__ src,
    const int* __restrict__ dst, const __half* __restrict__ h2,
    const float* __restrict__ cbuf, float* __restrict__ out)
{
    __shared__ float sv[17];
    if (threadIdx.x < 16) sv[threadIdx.x] = cbuf[32 + threadIdx.x];
    if (threadIdx.x == 16) sv[16] = cbuf[48];
    __syncthreads();
    const int e = blockIdx.x * 256 + threadIdx.x;
    if (e >= NE) return;
    const int s = src[e], d = dst[e];
    const uint4* hs = (const uint4*)(h2 + (size_t)s * 16);
    const uint4* hd = (const uint4*)(h2 + (size_t)d * 16);
    float acc = sv[16];
    const uint4 a0 = hs[0], a1 = hs[1];
    const uint4 b0 = hd[0], b1 = hd[1];
    const unsigned aw[8] = {a0.x, a0.y, a0.z, a0.w, a1.x, a1.y, a1.z, a1.w};
    const unsigned bw[8] = {b0.x, b0.y, b0.z, b0.w, b1.x, b1.y, b1.z, b1.w};
#pragma unroll
    for (int qq = 0; qq < 8; ++qq) {
        const float2 a = unpackh2(aw[qq]);
        const float2 b = unpackh2(bw[qq]);
        acc = fmaf(a.x * b.x, sv[qq * 2 + 0], acc);
        acc = fmaf(a.y * b.y, sv[qq * 2 + 1], acc);
    }
    out[e] = 1.0f / (1.0f + __expf(-acc));
}

extern "C" void kernel_launch(void* const* d_in, const int* in_sizes, int n_in,
                              void* d_out, int out_size, void* d_ws, size_t ws_size,
                              hipStream_t stream)
{
    const float* x    = (const float*)d_in[0];
    const int*   ei   = (const int*)d_in[1];
    const float* w1l  = (const float*)d_in[2];
    const float* w1r  = (const float*)d_in[3];
    const float* b1   = (const float*)d_in[4];
    const float* w2l  = (const float*)d_in[5];
    const float* w2r  = (const float*)d_in[6];
    const float* b2   = (const float*)d_in[7];
    const float* fc1w = (const float*)d_in[8];
    const float* fc1b = (const float*)d_in[9];
    const float* fc2w = (const float*)d_in[10];
    const float* fc2b = (const float*)d_in[11];
    float* out = (float*)d_out;

    const int* src = ei;
    const int* dst = ei + NE;

    // workspace layout (int units, 64B-align each array)
    int* W = (int*)d_ws;
    size_t o = 0;
#define ALIGN16() o = (o + 15) & ~(size_t)15
    int* mat    = W + o; o += (size_t)ABLK * NB; ALIGN16();
    int* bbase  = W + o; o += NB + 1;            ALIGN16();
    int* rowptr = W + o; o += NN + 1;            ALIGN16();
    unsigned* part = (unsigned*)(W + o); o += NE; ALIGN16();
    int* cols   = W + o; o += NE;                ALIGN16();
    float* A    = (float*)(W + o); o += 8192;    ALIGN16();
    unsigned short* ATh = (unsigned short*)(W + o); o += 4096; ALIGN16();
    unsigned short* ATl = (unsigned short*)(W + o); o += 4096; ALIGN16();
    float* cbuf = (float*)(W + o); o += 64;      ALIGN16();
    __half* p   = (__half*)(W + o); o += (size_t)NN * 16; ALIGN16();  // NN*32 halves
    float* q    = (float*)(W + o); o += (size_t)NN * 32;  ALIGN16();
    __half* g   = (__half*)(W + o); o += (size_t)NN * 8;  ALIGN16();  // NN*16 halves
    float* r    = (float*)(W + o); o += (size_t)NN * 16;  ALIGN16();
    __half* h2  = (__half*)(W + o); o += (size_t)NN * 8;  ALIGN16();  // NN*16 halves

    precomp_A<<<128, 64, 0, stream>>>(w1l, w1r, w2l, w2r, A);
    convA<<<32, 256, 0, stream>>>(A, ATh, ATl);
    precomp_consts<<<1, 64, 0, stream>>>(b1, w2l, w2r, fc1w, fc1b, fc2w, fc2b, cbuf);

    // bucketed CSR build
    partA_count<<<ABLK, 256, 0, stream>>>(dst, mat);
    partA_scan<<<1, 256, 0, stream>>>(mat, bbase);
    partA_scatter<<<ABLK, 256, 0, stream>>>(src, dst, mat, part);
    partB_build<<<NB, 512, 0, stream>>>(part, bbase, rowptr, cols);

    // dense projection (MFMA)
    gemm_mfma<<<(NN + 63) / 64, 256, 0, stream>>>(x, ATh, ATl, p, q);

    // aggregations (gather, no fp atomics)
    agg1_csr<<<(NN + 7) / 8, 256, 0, stream>>>(rowptr, cols, p, q, cbuf, g, r);
    agg2_csr<<<(NN + 15) / 16, 256, 0, stream>>>(rowptr, cols, g, r, b2, h2);

    // head
    edge_mlp<<<NE / 256, 256, 0, stream>>>(src, dst, h2, cbuf, out);
}

// Round 7
// 189.507 us; speedup vs baseline: 3.9182x; 1.0960x over previous
//
#include <hip/hip_runtime.h>
#include <hip/hip_fp16.h>
#include <math.h>

#define NN 100000
#define NE 1600000

#define NB   196        // buckets = ceil(NN/512); bucket = dst >> 9
#define BKN  512        // nodes per bucket
#define ABLK 128        // partition blocks
#define EPB  ((NE + ABLK - 1) / ABLK)   // 12500 edges per partition block

typedef __attribute__((ext_vector_type(8))) short bf16x8;
typedef __attribute__((ext_vector_type(4))) float f32x4;

__device__ __forceinline__ unsigned short f2bf(float f) {
    unsigned u = __builtin_bit_cast(unsigned, f);
    u += 0x7fffu + ((u >> 16) & 1u);           // RNE
    return (unsigned short)(u >> 16);
}
__device__ __forceinline__ float bf2f(unsigned short h) {
    unsigned u = ((unsigned)h) << 16;
    return __builtin_bit_cast(float, u);
}
__device__ __forceinline__ float2 unpackh2(unsigned w) {
    const __half2 h = __builtin_bit_cast(__half2, w);
    return __half22float2(h);
}

// ---- A[128][64] = [w1l@w2l | w1l@w2r | w1r@w2l | w1r@w2r]
__global__ __launch_bounds__(64) void precomp_A(const float* __restrict__ w1l,
    const float* __restrict__ w1r, const float* __restrict__ w2l,
    const float* __restrict__ w2r, float* __restrict__ A)
{
    __shared__ float sl[64], sr[64];
    const int k = blockIdx.x;
    const int j = threadIdx.x;
    sl[j] = w1l[k * 64 + j];
    sr[j] = w1r[k * 64 + j];
    __syncthreads();
    const int sel = j >> 4, jj = j & 15;
    const float* row = (sel < 2) ? sl : sr;
    const float* w2  = (sel & 1) ? w2r : w2l;
    float acc = 0.f;
#pragma unroll
    for (int m = 0; m < 64; ++m) acc = fmaf(row[m], w2[m * 16 + jj], acc);
    A[k * 64 + j] = acc;
}

// ---- AT (transposed, bf16 hi/lo): ATh/ATl[col][k]
__global__ __launch_bounds__(256) void convA(const float* __restrict__ A,
    unsigned short* __restrict__ ATh, unsigned short* __restrict__ ATl)
{
    const int i = blockIdx.x * 256 + threadIdx.x;
    if (i >= 8192) return;
    const int col = i >> 7, k = i & 127;
    const float v = A[k * 64 + col];
    const unsigned short h = f2bf(v);
    ATh[col * 128 + k] = h;
    ATl[col * 128 + k] = f2bf(v - bf2f(h));
}

// ---- cbuf: [0:16)=b1@w2l  [16:32)=b1@w2r  [32:48)=v=fc1w@fc2w  [48]=c
__global__ void precomp_consts(const float* __restrict__ b1,
    const float* __restrict__ w2l, const float* __restrict__ w2r,
    const float* __restrict__ fc1w, const float* __restrict__ fc1b,
    const float* __restrict__ fc2w, const float* __restrict__ fc2b,
    float* __restrict__ cbuf)
{
    const int j = threadIdx.x;
    if (j < 16) {
        float a = 0.f;
        for (int m = 0; m < 64; ++m) a = fmaf(b1[m], w2l[m * 16 + j], a);
        cbuf[j] = a;
    } else if (j < 32) {
        const int jj = j - 16;
        float a = 0.f;
        for (int m = 0; m < 64; ++m) a = fmaf(b1[m], w2r[m * 16 + jj], a);
        cbuf[j] = a;
    } else if (j < 48) {
        const int k = j - 32;
        float a = 0.f;
        for (int m = 0; m < 8; ++m) a = fmaf(fc1w[k * 8 + m], fc2w[m], a);
        cbuf[j] = a;
    } else if (j == 48) {
        float a = fc2b[0];
        for (int m = 0; m < 8; ++m) a = fmaf(fc1b[m], fc2w[m], a);
        cbuf[48] = a;
    }
}

// ---- MFMA GEMM: y = x @ A (bf16 3-term split).
//      p (cols 0..31) -> int8 + per-row scale;  q (cols 32..63) -> fp16
#define LDST 136
__global__ __launch_bounds__(256) void gemm_mfma(const float* __restrict__ x,
    const unsigned short* __restrict__ ATh, const unsigned short* __restrict__ ATl,
    signed char* __restrict__ p8, float* __restrict__ pscale,
    __half* __restrict__ qh)
{
    __shared__ unsigned short sAh[64 * LDST];
    __shared__ unsigned short sAl[64 * LDST];
    const int tid = threadIdx.x;
    for (int i = tid; i < 1024; i += 256) {
        const int row = i >> 4, ch = i & 15;
        const uint4 vh = *(const uint4*)(ATh + row * 128 + ch * 8);
        const uint4 vl = *(const uint4*)(ATl + row * 128 + ch * 8);
        *(uint4*)(sAh + row * LDST + ch * 8) = vh;
        *(uint4*)(sAl + row * LDST + ch * 8) = vl;
    }
    __syncthreads();

    const int wave = tid >> 6;
    const int lane = tid & 63;
    const int lr = lane & 15;
    const int lg = lane >> 4;

    bf16x8 bh[4][4], bl[4][4];
#pragma unroll
    for (int ct = 0; ct < 4; ++ct) {
        const int col = ct * 16 + lr;
#pragma unroll
        for (int ks = 0; ks < 4; ++ks) {
            const int k0 = ks * 32 + lg * 8;
            bh[ct][ks] = *(const bf16x8*)(sAh + col * LDST + k0);
            bl[ct][ks] = *(const bf16x8*)(sAl + col * LDST + k0);
        }
    }

    const int tilebase = blockIdx.x * 64;
    const int xrowidx = tilebase + wave * 16 + lr;
    const float* xrow = x + (size_t)(xrowidx < NN ? xrowidx : NN - 1) * 128;

    f32x4 acc[4] = {f32x4{0,0,0,0}, f32x4{0,0,0,0}, f32x4{0,0,0,0}, f32x4{0,0,0,0}};
#pragma unroll
    for (int ks = 0; ks < 4; ++ks) {
        const int k0 = ks * 32 + lg * 8;
        const float4 v0 = *(const float4*)(xrow + k0);
        const float4 v1 = *(const float4*)(xrow + k0 + 4);
        const float vv[8] = {v0.x, v0.y, v0.z, v0.w, v1.x, v1.y, v1.z, v1.w};
        bf16x8 xh, xl;
#pragma unroll
        for (int j = 0; j < 8; ++j) {
            const unsigned short h = f2bf(vv[j]);
            xh[j] = (short)h;
            xl[j] = (short)f2bf(vv[j] - bf2f(h));
        }
#pragma unroll
        for (int ct = 0; ct < 4; ++ct) {
            acc[ct] = __builtin_amdgcn_mfma_f32_16x16x32_bf16(xh, bh[ct][ks], acc[ct], 0, 0, 0);
            acc[ct] = __builtin_amdgcn_mfma_f32_16x16x32_bf16(xh, bl[ct][ks], acc[ct], 0, 0, 0);
            acc[ct] = __builtin_amdgcn_mfma_f32_16x16x32_bf16(xl, bh[ct][ks], acc[ct], 0, 0, 0);
        }
    }

    // D layout: row = tilebase + wave*16 + lg*4 + rg; col = ct*16 + lr
#pragma unroll
    for (int rg = 0; rg < 4; ++rg) {
        float m = fmaxf(fabsf(acc[0][rg]), fabsf(acc[1][rg]));
#pragma unroll
        for (int d = 1; d < 16; d <<= 1) m = fmaxf(m, __shfl_xor(m, d, 64));
        m = fmaxf(m, 1e-20f);
        const float scl = m * (1.0f / 127.0f);
        const float inv = 127.0f / m;
        const int nrow = tilebase + wave * 16 + lg * 4 + rg;
        if (nrow < NN) {
            const int q0 = __float2int_rn(acc[0][rg] * inv);
            const int q1 = __float2int_rn(acc[1][rg] * inv);
            p8[(size_t)nrow * 32 + lr]      = (signed char)q0;
            p8[(size_t)nrow * 32 + 16 + lr] = (signed char)q1;
            if (lr == 0) pscale[nrow] = scl;
            qh[(size_t)nrow * 32 + lr]      = __float2half(acc[2][rg]);
            qh[(size_t)nrow * 32 + 16 + lr] = __float2half(acc[3][rg]);
        }
    }
}

// ============ bucketed CSR build ============
__global__ __launch_bounds__(256) void partA_count(const int* __restrict__ dst,
    int* __restrict__ mat)
{
    __shared__ int h[NB];
    for (int i = threadIdx.x; i < NB; i += 256) h[i] = 0;
    __syncthreads();
    const int a = blockIdx.x;
    const int beg = a * EPB;
    const int end = (beg + EPB < NE) ? beg + EPB : NE;
    for (int e = beg + threadIdx.x; e < end; e += 256)
        atomicAdd(&h[dst[e] >> 9], 1);
    __syncthreads();
    for (int i = threadIdx.x; i < NB; i += 256) mat[a * NB + i] = h[i];
}

__global__ __launch_bounds__(256) void partA_scan(int* __restrict__ mat,
    int* __restrict__ bbase)
{
    __shared__ int tot[NB];
    const int b = threadIdx.x;
    if (b < NB) {
        int run = 0;
        for (int a = 0; a < ABLK; ++a) {
            const int t = mat[a * NB + b];
            mat[a * NB + b] = run;
            run += t;
        }
        tot[b] = run;
    }
    __syncthreads();
    if (threadIdx.x == 0) {
        int acc = 0;
        for (int i = 0; i < NB; ++i) {
            const int t = tot[i];
            tot[i] = acc;
            bbase[i] = acc;
            acc += t;
        }
        bbase[NB] = acc;
    }
    __syncthreads();
    if (b < NB) {
        const int base = tot[b];
        for (int a = 0; a < ABLK; ++a) mat[a * NB + b] += base;
    }
}

// packed entry: (src << 9) | local_dst
__global__ __launch_bounds__(256) void partA_scatter(const int* __restrict__ src,
    const int* __restrict__ dst, const int* __restrict__ mat,
    unsigned* __restrict__ part)
{
    __shared__ int cur[NB];
    const int a = blockIdx.x;
    for (int i = threadIdx.x; i < NB; i += 256) cur[i] = mat[a * NB + i];
    __syncthreads();
    const int beg = a * EPB;
    const int end = (beg + EPB < NE) ? beg + EPB : NE;
    for (int e = beg + threadIdx.x; e < end; e += 256) {
        const int s = src[e], d = dst[e];
        const int pos = atomicAdd(&cur[d >> 9], 1);
        part[pos] = ((unsigned)s << 9) | (unsigned)(d & 511);
    }
}

__global__ __launch_bounds__(512) void partB_build(const unsigned* __restrict__ part,
    const int* __restrict__ bbase, int* __restrict__ rowptr, int* __restrict__ cols)
{
    __shared__ int h[BKN];
    __shared__ int cur[BKN];
    const int b = blockIdx.x;
    const int beg = bbase[b], end = bbase[b + 1];
    h[threadIdx.x] = 0;
    __syncthreads();
    for (int e = beg + threadIdx.x; e < end; e += 512)
        atomicAdd(&h[part[e] & 511u], 1);
    __syncthreads();
    const int v = h[threadIdx.x];
    for (int off = 1; off < BKN; off <<= 1) {
        const int t = (threadIdx.x >= off) ? h[threadIdx.x - off] : 0;
        __syncthreads();
        h[threadIdx.x] += t;
        __syncthreads();
    }
    const int excl = h[threadIdx.x] - v;
    cur[threadIdx.x] = excl;
    const int node = b * BKN + threadIdx.x;
    if (node < NN) rowptr[node] = beg + excl;
    if (b == NB - 1 && threadIdx.x == 0) rowptr[NN] = NE;
    __syncthreads();
    for (int e = beg + threadIdx.x; e < end; e += 512) {
        const unsigned w = part[e];
        const int pos = atomicAdd(&cur[w & 511u], 1);
        cols[beg + pos] = (int)(w >> 9);
    }
}

// ============ aggregation via CSR ============
// layer 1: p int8 + per-row scale; q fp16. g -> fp16, r -> fp16
__global__ __launch_bounds__(256) void agg1_csr(const int* __restrict__ rowptr,
    const int* __restrict__ cols, const signed char* __restrict__ p8,
    const float* __restrict__ pscale, const __half* __restrict__ qh,
    const float* __restrict__ cbuf, __half* __restrict__ g, __half* __restrict__ r)
{
    const int node = blockIdx.x * 8 + (threadIdx.x >> 5);
    if (node >= NN) return;
    const int f = threadIdx.x & 31;
    const int beg = rowptr[node], end = rowptr[node + 1];
    float acc = 0.f;
    int j = beg;
    for (; j + 3 < end; j += 4) {
        const int s0 = cols[j], s1 = cols[j + 1], s2 = cols[j + 2], s3 = cols[j + 3];
        const float v0 = (float)p8[(size_t)s0 * 32 + f] * pscale[s0];
        const float v1 = (float)p8[(size_t)s1 * 32 + f] * pscale[s1];
        const float v2 = (float)p8[(size_t)s2 * 32 + f] * pscale[s2];
        const float v3 = (float)p8[(size_t)s3 * 32 + f] * pscale[s3];
        acc += (v0 + v1) + (v2 + v3);
    }
    for (; j < end; ++j) {
        const int s = cols[j];
        acc += (float)p8[(size_t)s * 32 + f] * pscale[s];
    }
    const float dg = (float)(end - beg);
    const float m = acc * (1.0f / fmaxf(dg, 1.0f));
    const float val = m + __half2float(qh[(size_t)node * 32 + f]) + cbuf[f];
    if (f < 16) g[(size_t)node * 16 + f] = __float2half(val);
    else        r[(size_t)node * 16 + (f - 16)] = __float2half(val);
}

// layer 2: g fp16 gather; h2 = mean + r + b2 -> fp16
__global__ __launch_bounds__(256) void agg2_csr(const int* __restrict__ rowptr,
    const int* __restrict__ cols, const __half* __restrict__ g,
    const __half* __restrict__ r, const float* __restrict__ b2,
    __half* __restrict__ h2)
{
    const int node = blockIdx.x * 16 + (threadIdx.x >> 4);
    if (node >= NN) return;
    const int f = threadIdx.x & 15;
    const int beg = rowptr[node], end = rowptr[node + 1];
    float acc = 0.f;
    int j = beg;
    for (; j + 3 < end; j += 4) {
        const int s0 = cols[j], s1 = cols[j + 1], s2 = cols[j + 2], s3 = cols[j + 3];
        const float v0 = __half2float(g[(size_t)s0 * 16 + f]);
        const float v1 = __half2float(g[(size_t)s1 * 16 + f]);
        const float v2 = __half2float(g[(size_t)s2 * 16 + f]);
        const float v3 = __half2float(g[(size_t)s3 * 16 + f]);
        acc += (v0 + v1) + (v2 + v3);
    }
    for (; j < end; ++j) acc += __half2float(g[(size_t)cols[j] * 16 + f]);
    const float dg = (float)(end - beg);
    const float val = acc * (1.0f / fmaxf(dg, 1.0f))
                    + __half2float(r[(size_t)node * 16 + f]) + b2[f];
    h2[(size_t)node * 16 + f] = __float2half(val);
}

// ---- out = sigmoid( sum_k h2[s][k]*h2[d][k]*v[k] + c )
__global__ __launch_bounds__(256) void edge_mlp(const int* __restrict__ src,
    const int* __restrict__ dst, const __half* __restrict__ h2,
    const float* __restrict__ cbuf, float* __restrict__ out)
{
    __shared__ float sv[17];
    if (threadIdx.x < 16) sv[threadIdx.x] = cbuf[32 + threadIdx.x];
    if (threadIdx.x == 16) sv[16] = cbuf[48];
    __syncthreads();
    const int e = blockIdx.x * 256 + threadIdx.x;
    if (e >= NE) return;
    const int s = src[e], d = dst[e];
    const uint4* hs = (const uint4*)(h2 + (size_t)s * 16);
    const uint4* hd = (const uint4*)(h2 + (size_t)d * 16);
    float acc = sv[16];
    const uint4 a0 = hs[0], a1 = hs[1];
    const uint4 b0 = hd[0], b1 = hd[1];
    const unsigned aw[8] = {a0.x, a0.y, a0.z, a0.w, a1.x, a1.y, a1.z, a1.w};
    const unsigned bw[8] = {b0.x, b0.y, b0.z, b0.w, b1.x, b1.y, b1.z, b1.w};
#pragma unroll
    for (int qq = 0; qq < 8; ++qq) {
        const float2 a = unpackh2(aw[qq]);
        const float2 b = unpackh2(bw[qq]);
        acc = fmaf(a.x * b.x, sv[qq * 2 + 0], acc);
        acc = fmaf(a.y * b.y, sv[qq * 2 + 1], acc);
    }
    out[e] = 1.0f / (1.0f + __expf(-acc));
}

extern "C" void kernel_launch(void* const* d_in, const int* in_sizes, int n_in,
                              void* d_out, int out_size, void* d_ws, size_t ws_size,
                              hipStream_t stream)
{
    const float* x    = (const float*)d_in[0];
    const int*   ei   = (const int*)d_in[1];
    const float* w1l  = (const float*)d_in[2];
    const float* w1r  = (const float*)d_in[3];
    const float* b1   = (const float*)d_in[4];
    const float* w2l  = (const float*)d_in[5];
    const float* w2r  = (const float*)d_in[6];
    const float* b2   = (const float*)d_in[7];
    const float* fc1w = (const float*)d_in[8];
    const float* fc1b = (const float*)d_in[9];
    const float* fc2w = (const float*)d_in[10];
    const float* fc2b = (const float*)d_in[11];
    float* out = (float*)d_out;

    const int* src = ei;
    const int* dst = ei + NE;

    // workspace layout (int units, 64B-align each array)
    int* W = (int*)d_ws;
    size_t o = 0;
#define ALIGN16() o = (o + 15) & ~(size_t)15
    int* mat    = W + o; o += (size_t)ABLK * NB; ALIGN16();
    int* bbase  = W + o; o += NB + 1;            ALIGN16();
    int* rowptr = W + o; o += NN + 1;            ALIGN16();
    unsigned* part = (unsigned*)(W + o); o += NE; ALIGN16();
    int* cols   = W + o; o += NE;                ALIGN16();
    float* A    = (float*)(W + o); o += 8192;    ALIGN16();
    unsigned short* ATh = (unsigned short*)(W + o); o += 4096; ALIGN16();
    unsigned short* ATl = (unsigned short*)(W + o); o += 4096; ALIGN16();
    float* cbuf = (float*)(W + o); o += 64;      ALIGN16();
    signed char* p8 = (signed char*)(W + o); o += (size_t)NN * 8;  ALIGN16(); // NN*32 bytes
    float* pscale   = (float*)(W + o); o += NN;  ALIGN16();
    __half* qh  = (__half*)(W + o); o += (size_t)NN * 16; ALIGN16();  // NN*32 halves
    __half* g   = (__half*)(W + o); o += (size_t)NN * 8;  ALIGN16();  // NN*16 halves
    __half* r   = (__half*)(W + o); o += (size_t)NN * 8;  ALIGN16();
    __half* h2  = (__half*)(W + o); o += (size_t)NN * 8;  ALIGN16();

    precomp_A<<<128, 64, 0, stream>>>(w1l, w1r, w2l, w2r, A);
    convA<<<32, 256, 0, stream>>>(A, ATh, ATl);
    precomp_consts<<<1, 64, 0, stream>>>(b1, w2l, w2r, fc1w, fc1b, fc2w, fc2b, cbuf);

    // bucketed CSR build
    partA_count<<<ABLK, 256, 0, stream>>>(dst, mat);
    partA_scan<<<1, 256, 0, stream>>>(mat, bbase);
    partA_scatter<<<ABLK, 256, 0, stream>>>(src, dst, mat, part);
    partB_build<<<NB, 512, 0, stream>>>(part, bbase, rowptr, cols);

    // dense projection (MFMA, int8 payload epilogue)
    gemm_mfma<<<(NN + 63) / 64, 256, 0, stream>>>(x, ATh, ATl, p8, pscale, qh);

    // aggregations (gather, no fp atomics)
    agg1_csr<<<(NN + 7) / 8, 256, 0, stream>>>(rowptr, cols, p8, pscale, qh, cbuf, g, r);
    agg2_csr<<<(NN + 15) / 16, 256, 0, stream>>>(rowptr, cols, g, r, b2, h2);

    // head
    edge_mlp<<<NE / 256, 256, 0, stream>>>(src, dst, h2, cbuf, out);
}